// Round 2
// baseline (6196.924 us; speedup 1.0000x reference)
//
#include <hip/hip_runtime.h>
#include <cstddef>
#include <cstdint>

#define NPTS   2048
#define NBATCH 16
#define NG     128
#define NM     32
#define DMODEL 384
#define DINNER 768
#define DSTATE 16
#define DTRANK 24
#define NLAYER 12
#define LEPS   1e-5f
#define NTOK   (NBATCH*NG)      /* 2048 tokens */
#define NROW   (NTOK*NM)        /* 65536 point rows */
#define FLTMAX 3.402823466e+38f

// ---------------- FPS: one wave per batch, shuffle argmax reduce ----------------
// Matches jnp semantics: d = ((dx*dx+dy*dy)+dz*dz) with no FMA contraction (_rn ops),
// dmin = min accumulate, argmax tie-break = lowest index.
__global__ __launch_bounds__(64) void fps_kernel(const float* __restrict__ pts, int* __restrict__ idx){
  const int b = blockIdx.x;
  const int lane = threadIdx.x;
  const float* P = pts + (size_t)b*NPTS*3;
  float px[32], py[32], pz[32], dmin[32];
  #pragma unroll
  for (int j=0;j<32;j++){
    int p = lane + j*64;
    px[j]=P[p*3+0]; py[j]=P[p*3+1]; pz[j]=P[p*3+2];
    dmin[j]=1e10f;
  }
  int cur = 0;
  if (lane==0) idx[b*NG+0] = 0;
  for (int it=1; it<NG; ++it){
    float lx = P[cur*3+0], ly = P[cur*3+1], lz = P[cur*3+2];
    float best = -1.0f; int bi = 0;
    #pragma unroll
    for (int j=0;j<32;j++){
      float dx=__fsub_rn(px[j],lx), dy=__fsub_rn(py[j],ly), dz=__fsub_rn(pz[j],lz);
      float d = __fadd_rn(__fadd_rn(__fmul_rn(dx,dx),__fmul_rn(dy,dy)),__fmul_rn(dz,dz));
      float dm = fminf(dmin[j], d);
      dmin[j]=dm;
      int p = lane + j*64;
      if (dm > best || (dm == best && p < bi)) { best = dm; bi = p; }
    }
    #pragma unroll
    for (int m=1;m<64;m<<=1){
      float ov = __shfl_xor(best, m);
      int   oi = __shfl_xor(bi, m);
      if (ov > best || (ov == best && oi < bi)){ best=ov; bi=oi; }
    }
    cur = __builtin_amdgcn_readfirstlane(bi);
    if (lane==0) idx[b*NG+it] = cur;
  }
}

// ---------------- kNN grouping: block per (b,g) center ----------------
// d = (cs + ps) - 2*dot, exact _rn order to match reference; 32 masked argmins
// reproduce top_k's selected SET (order irrelevant: downstream is perm-invariant over M).
__global__ __launch_bounds__(256) void knn_kernel(const float* __restrict__ pts, const int* __restrict__ idx,
                                                  float* __restrict__ pg, float* __restrict__ centerb){
  __shared__ float sx[NPTS], sy[NPTS], sz[NPTS], sd[NPTS];
  __shared__ float rv[256]; __shared__ int ri[256];
  const int bid = blockIdx.x;       // b*128+g
  const int b = bid >> 7;
  const int t = threadIdx.x;
  const float* P = pts + (size_t)b*NPTS*3;
  const int ci = idx[bid];
  const float cx = P[ci*3+0], cy = P[ci*3+1], cz = P[ci*3+2];
  const float cs = __fadd_rn(__fadd_rn(__fmul_rn(cx,cx),__fmul_rn(cy,cy)),__fmul_rn(cz,cz));
  for (int p=t; p<NPTS; p+=256){
    float x=P[p*3+0], y=P[p*3+1], z=P[p*3+2];
    float ps  = __fadd_rn(__fadd_rn(__fmul_rn(x,x),__fmul_rn(y,y)),__fmul_rn(z,z));
    float dot = __fadd_rn(__fadd_rn(__fmul_rn(cx,x),__fmul_rn(cy,y)),__fmul_rn(cz,z));
    float d = __fsub_rn(__fadd_rn(cs,ps), __fmul_rn(2.0f,dot));
    sx[p]=x; sy[p]=y; sz[p]=z; sd[p]=d;
  }
  if (t==0){ centerb[bid*3+0]=cx; centerb[bid*3+1]=cy; centerb[bid*3+2]=cz; }
  __syncthreads();
  for (int m=0;m<NM;m++){
    float bv = FLTMAX; int bp = NPTS;
    for (int p=t;p<NPTS;p+=256){
      float v = sd[p];
      if (v < bv || (v == bv && p < bp)){ bv=v; bp=p; }
    }
    rv[t]=bv; ri[t]=bp;
    __syncthreads();
    for (int s=128;s>0;s>>=1){
      if (t<s){
        float ov=rv[t+s]; int oi=ri[t+s];
        if (ov < rv[t] || (ov == rv[t] && oi < ri[t])){ rv[t]=ov; ri[t]=oi; }
      }
      __syncthreads();
    }
    if (t==0){
      int sel = ri[0];
      size_t orow = ((size_t)bid*NM + m)*3;
      pg[orow+0]=__fsub_rn(sx[sel],cx);
      pg[orow+1]=__fsub_rn(sy[sel],cy);
      pg[orow+2]=__fsub_rn(sz[sel],cz);
      sd[sel]=FLTMAX;
    }
    __syncthreads();
  }
}

// ---------------- folded BN coefficients ----------------
__global__ void prep_kernel(const float* bn1g, const float* bn1b, const float* bn1m, const float* bn1v, const float* e1b,
                            const float* bn2g, const float* bn2b, const float* bn2m, const float* bn2v, const float* e3b,
                            float* a1, float* b1, float* a2, float* b2){
  int t = threadIdx.x;
  if (t<128){ float a = bn1g[t]/sqrtf(bn1v[t]+LEPS); a1[t]=a; b1[t]=(e1b[t]-bn1m[t])*a+bn1b[t]; }
  if (t<512){ float a = bn2g[t]/sqrtf(bn2v[t]+LEPS); a2[t]=a; b2[t]=(e3b[t]-bn2m[t])*a+bn2b[t]; }
}

// ---------------- tiny K=3 layers ----------------
__global__ __launch_bounds__(256) void e1_kernel(const float* __restrict__ pg, const float* __restrict__ w,
                                                 const float* __restrict__ a1, const float* __restrict__ b1,
                                                 float* __restrict__ f1){
  int gid = blockIdx.x*256 + threadIdx.x;      // NROW*128
  int row = gid >> 7, c = gid & 127;
  float x = pg[(size_t)row*3+0], y = pg[(size_t)row*3+1], z = pg[(size_t)row*3+2];
  float v = x*w[c*3+0] + y*w[c*3+1] + z*w[c*3+2];
  f1[gid] = fmaxf(v*a1[c]+b1[c], 0.0f);
}

__global__ __launch_bounds__(256) void p1_kernel(const float* __restrict__ center, const float* __restrict__ w,
                                                 const float* __restrict__ bias, float* __restrict__ o){
  int gid = blockIdx.x*256 + threadIdx.x;      // NTOK*128
  int row = gid >> 7, c = gid & 127;
  float x = center[(size_t)row*3+0], y = center[(size_t)row*3+1], z = center[(size_t)row*3+2];
  float v = x*w[c*3+0]+y*w[c*3+1]+z*w[c*3+2] + bias[c];
  o[gid] = 0.5f*v*(1.0f+erff(v*0.70710678118654752f));  // exact gelu
}

// ---------------- generic fp32 tiled GEMM: C[M,N] = A[M,K] @ W[N,K]^T (+epilogue) ----------------
// EPI: 0=none, 1=+bias(P1), 2=relu(acc*P1[n]+P2[n]).  CONCAT: A cols 0..255 from A2(fg, row>>5), 256.. from A(f2).
// Requires M%128==0, K%16==0; N arbitrary (guarded).
template<int EPI, bool CONCAT>
__global__ __launch_bounds__(256) void gemm_nt(const float* __restrict__ A, const float* __restrict__ A2,
                                               const float* __restrict__ W, const float* __restrict__ P1,
                                               const float* __restrict__ P2, float* __restrict__ C,
                                               int M, int N, int K){
  __shared__ float As[16][132];
  __shared__ float Ws[16][132];
  const int tid = threadIdx.x;
  const int bm = blockIdx.y*128, bn = blockIdx.x*128;
  const int tx = tid & 15, ty = tid >> 4;
  float acc[8][8];
  #pragma unroll
  for (int i=0;i<8;i++)
    #pragma unroll
    for (int j=0;j<8;j++) acc[i][j]=0.f;
  for (int kt=0; kt<K; kt+=16){
    #pragma unroll
    for (int l=0;l<2;l++){
      int i = tid + l*256;
      int row = i >> 2;
      int kq = (i & 3)*4;
      int rg = bm + row, kg = kt + kq;
      float4 va;
      if (CONCAT){
        if (kg < 256) va = *(const float4*)(A2 + ((size_t)(rg>>5))*256 + kg);
        else          va = *(const float4*)(A  + (size_t)rg*256 + (kg-256));
      } else {
        va = *(const float4*)(A + (size_t)rg*K + kg);
      }
      As[kq+0][row]=va.x; As[kq+1][row]=va.y; As[kq+2][row]=va.z; As[kq+3][row]=va.w;
      int nr = bn + row;
      float4 vw = make_float4(0.f,0.f,0.f,0.f);
      if (nr < N) vw = *(const float4*)(W + (size_t)nr*K + kg);
      Ws[kq+0][row]=vw.x; Ws[kq+1][row]=vw.y; Ws[kq+2][row]=vw.z; Ws[kq+3][row]=vw.w;
    }
    __syncthreads();
    #pragma unroll
    for (int k=0;k<16;k++){
      float a[8], bb[8];
      *(float4*)&a[0]  = *(const float4*)&As[k][ty*4];
      *(float4*)&a[4]  = *(const float4*)&As[k][64+ty*4];
      *(float4*)&bb[0] = *(const float4*)&Ws[k][tx*4];
      *(float4*)&bb[4] = *(const float4*)&Ws[k][64+tx*4];
      #pragma unroll
      for (int i=0;i<8;i++)
        #pragma unroll
        for (int j=0;j<8;j++) acc[i][j] += a[i]*bb[j];
    }
    __syncthreads();
  }
  #pragma unroll
  for (int i=0;i<8;i++){
    int rg = bm + ((i<4)? (ty*4+i) : (64+ty*4+i-4));
    #pragma unroll
    for (int j=0;j<8;j++){
      int n = bn + ((j<4)? (tx*4+j) : (64+tx*4+j-4));
      if (n < N){
        float v = acc[i][j];
        if (EPI==1) v += P1[n];
        else if (EPI==2){ v = fmaxf(v*P1[n]+P2[n], 0.f); }
        C[(size_t)rg*N + n] = v;
      }
    }
  }
}

// ---------------- max-pools ----------------
__global__ __launch_bounds__(256) void fgpool_kernel(const float* __restrict__ f2, float* __restrict__ fg){
  int g = blockIdx.x, c = threadIdx.x;
  float m = -FLTMAX;
  for (int mm=0;mm<NM;mm++) m = fmaxf(m, f2[((size_t)(g*NM+mm))*256 + c]);
  fg[(size_t)g*256+c]=m;
}
__global__ __launch_bounds__(384) void tokpool_kernel(const float* __restrict__ t4, const float* __restrict__ pos,
                                                      float* __restrict__ h){
  int g = blockIdx.x, c = threadIdx.x;
  float m = -FLTMAX;
  for (int mm=0;mm<NM;mm++) m = fmaxf(m, t4[((size_t)(g*NM+mm))*DMODEL + c]);
  h[(size_t)g*DMODEL+c] = m + pos[(size_t)g*DMODEL+c];
}

// ---------------- LayerNorm (+residual update) ----------------
template<bool ADD>
__global__ __launch_bounds__(128) void ln_kernel(const float* __restrict__ hbuf, float* __restrict__ res,
                                                 float* __restrict__ xln, const float* __restrict__ gamma,
                                                 const float* __restrict__ beta){
  __shared__ float s[128];
  int row = blockIdx.x, t = threadIdx.x;
  const float* hr = hbuf + (size_t)row*DMODEL;
  float* rr = res + (size_t)row*DMODEL;
  float v[3]; float lsum=0.f;
  #pragma unroll
  for (int i=0;i<3;i++){ int c=t+i*128; float x=hr[c]; if(ADD) x+=rr[c]; v[i]=x; lsum+=x; }
  #pragma unroll
  for (int i=0;i<3;i++) rr[t+i*128]=v[i];
  s[t]=lsum; __syncthreads();
  for (int o=64;o>0;o>>=1){ if(t<o) s[t]+=s[t+o]; __syncthreads(); }
  float mean = s[0]*(1.0f/384.0f);
  __syncthreads();
  float l2=0.f;
  #pragma unroll
  for (int i=0;i<3;i++){ float dmu=v[i]-mean; l2+=dmu*dmu; }
  s[t]=l2; __syncthreads();
  for (int o=64;o>0;o>>=1){ if(t<o) s[t]+=s[t+o]; __syncthreads(); }
  float var = s[0]*(1.0f/384.0f);
  float rs = 1.0f/sqrtf(var+LEPS);
  #pragma unroll
  for (int i=0;i<3;i++){ int c=t+i*128; xln[(size_t)row*DMODEL+c] = (v[i]-mean)*rs*gamma[c]+beta[c]; }
}

__global__ __launch_bounds__(128) void final_ln_kernel(const float* __restrict__ hbuf, const float* __restrict__ res,
                                                       const float* __restrict__ gamma, const float* __restrict__ beta,
                                                       float* __restrict__ out){
  __shared__ float s[128];
  int row = blockIdx.x, t = threadIdx.x;
  const float* hr = hbuf + (size_t)row*DMODEL;
  const float* rr = res + (size_t)row*DMODEL;
  float v[3]; float lsum=0.f;
  #pragma unroll
  for (int i=0;i<3;i++){ int c=t+i*128; float x=hr[c]+rr[c]; v[i]=x; lsum+=x; }
  s[t]=lsum; __syncthreads();
  for (int o=64;o>0;o>>=1){ if(t<o) s[t]+=s[t+o]; __syncthreads(); }
  float mean = s[0]*(1.0f/384.0f);
  __syncthreads();
  float l2=0.f;
  #pragma unroll
  for (int i=0;i<3;i++){ float dmu=v[i]-mean; l2+=dmu*dmu; }
  s[t]=l2; __syncthreads();
  for (int o=64;o>0;o>>=1){ if(t<o) s[t]+=s[t+o]; __syncthreads(); }
  float var = s[0]*(1.0f/384.0f);
  float rs = 1.0f/sqrtf(var+LEPS);
  #pragma unroll
  for (int i=0;i<3;i++){ int c=t+i*128; out[(size_t)row*DMODEL+c] = (v[i]-mean)*rs*gamma[c]+beta[c]; }
}

// ---------------- depthwise causal conv(k=4) + silu ----------------
__global__ __launch_bounds__(256) void conv_kernel(const float* __restrict__ uz, const float* __restrict__ cw,
                                                   const float* __restrict__ cb, float* __restrict__ uc){
  int gid = blockIdx.x*256 + threadIdx.x;  // NTOK*DINNER
  int d = gid % DINNER;
  int rl = gid / DINNER;
  int l = rl & (NG-1);
  float acc = cb[d];
  #pragma unroll
  for (int k=0;k<4;k++){
    int l2 = l-3+k;
    if (l2 >= 0) acc += uz[(size_t)(rl-3+k)*1536 + d]*cw[d*4+k];
  }
  uc[gid] = acc/(1.0f+__expf(-acc));
}

// ---------------- dt = softplus(xbc[:, :24] @ dtw^T + dtb) ----------------
__global__ __launch_bounds__(256) void dtproj_kernel(const float* __restrict__ xbc, const float* __restrict__ dtw,
                                                     const float* __restrict__ dtb, float* __restrict__ dt){
  int gid = blockIdx.x*256 + threadIdx.x;  // NTOK*DINNER
  int d = gid % DINNER;
  int r = gid / DINNER;
  float acc = dtb[d];
  const float* xr = xbc + (size_t)r*56;
  #pragma unroll
  for (int j=0;j<DTRANK;j++) acc += xr[j]*dtw[d*DTRANK+j];
  dt[gid] = (acc > 20.0f) ? acc : log1pf(__expf(acc));
}

// ---------------- SSM scan + skip + gating: one thread per channel ----------------
__global__ __launch_bounds__(256) void scan_kernel(const float* __restrict__ uc, const float* __restrict__ dt,
                                                   const float* __restrict__ xbc, const float* __restrict__ uz,
                                                   const float* __restrict__ Alog, const float* __restrict__ Dp,
                                                   float* __restrict__ yg){
  int blk = blockIdx.x;          // NBATCH*3
  int b = blk/3, chunk = blk%3;
  int d = chunk*256 + threadIdx.x;
  float a[DSTATE];
  #pragma unroll
  for (int s=0;s<DSTATE;s++) a[s] = -expf(Alog[(size_t)d*DSTATE+s]);
  float D_ = Dp[d];
  float h[DSTATE];
  #pragma unroll
  for (int s=0;s<DSTATE;s++) h[s]=0.f;
  for (int l=0;l<NG;l++){
    int r = b*NG + l;
    float dtv = dt[(size_t)r*DINNER + d];
    float uv  = uc[(size_t)r*DINNER + d];
    float du = dtv*uv;
    const float* xb = xbc + (size_t)r*56;
    float4 B0 = *(const float4*)(xb+24), B1 = *(const float4*)(xb+28);
    float4 B2 = *(const float4*)(xb+32), B3 = *(const float4*)(xb+36);
    float4 C0 = *(const float4*)(xb+40), C1 = *(const float4*)(xb+44);
    float4 C2 = *(const float4*)(xb+48), C3 = *(const float4*)(xb+52);
    float Bs[16] = {B0.x,B0.y,B0.z,B0.w,B1.x,B1.y,B1.z,B1.w,B2.x,B2.y,B2.z,B2.w,B3.x,B3.y,B3.z,B3.w};
    float Cs[16] = {C0.x,C0.y,C0.z,C0.w,C1.x,C1.y,C1.z,C1.w,C2.x,C2.y,C2.z,C2.w,C3.x,C3.y,C3.z,C3.w};
    float y = 0.f;
    #pragma unroll
    for (int s=0;s<DSTATE;s++){
      float dA = __expf(dtv*a[s]);
      h[s] = dA*h[s] + du*Bs[s];
      y += h[s]*Cs[s];
    }
    float zv = uz[(size_t)r*1536 + DINNER + d];
    float sg = zv/(1.0f+__expf(-zv));
    yg[(size_t)r*DINNER + d] = (y + uv*D_)*sg;
  }
}

// ---------------- launch ----------------
extern "C" void kernel_launch(void* const* d_in, const int* in_sizes, int n_in,
                              void* d_out, int out_size, void* d_ws, size_t ws_size,
                              hipStream_t stream){
  const float* pts   = (const float*)d_in[0];
  const float* e1w   = (const float*)d_in[1];
  const float* e1b   = (const float*)d_in[2];
  const float* bn1g  = (const float*)d_in[3];
  const float* bn1b  = (const float*)d_in[4];
  const float* bn1m  = (const float*)d_in[5];
  const float* bn1v  = (const float*)d_in[6];
  const float* e2w   = (const float*)d_in[7];
  const float* e2b   = (const float*)d_in[8];
  const float* e3w   = (const float*)d_in[9];
  const float* e3b   = (const float*)d_in[10];
  const float* bn2g  = (const float*)d_in[11];
  const float* bn2b  = (const float*)d_in[12];
  const float* bn2m  = (const float*)d_in[13];
  const float* bn2v  = (const float*)d_in[14];
  const float* e4w   = (const float*)d_in[15];
  const float* e4b   = (const float*)d_in[16];
  const float* p1w   = (const float*)d_in[17];
  const float* p1b   = (const float*)d_in[18];
  const float* p2w   = (const float*)d_in[19];
  const float* p2b   = (const float*)d_in[20];
  const float* lng   = (const float*)d_in[21];
  const float* lnb   = (const float*)d_in[22];
  const float* inw   = (const float*)d_in[23];
  const float* convw = (const float*)d_in[24];
  const float* convb = (const float*)d_in[25];
  const float* xprojw= (const float*)d_in[26];
  const float* dtw   = (const float*)d_in[27];
  const float* dtb   = (const float*)d_in[28];
  const float* Alog  = (const float*)d_in[29];
  const float* Dp    = (const float*)d_in[30];
  const float* outw  = (const float*)d_in[31];
  const float* nfg   = (const float*)d_in[32];
  const float* nfb   = (const float*)d_in[33];
  float* out = (float*)d_out;

  char* w = (char*)d_ws;
  const size_t O_IDX   = 0;
  const size_t O_CENT  = 8192;
  const size_t O_PG    = O_CENT + 24576;
  const size_t O_A1    = O_PG + 786432;
  const size_t O_B1    = O_A1 + 512;
  const size_t O_A2    = O_B1 + 512;
  const size_t O_B2    = O_A2 + 2048;
  const size_t O_PG1   = O_B2 + 2048;
  const size_t O_POS   = O_PG1 + 1048576;
  const size_t O_H     = O_POS + 3145728;
  const size_t O_RES   = O_H + 3145728;
  const size_t O_F1    = O_RES + 3145728;
  const size_t O_F2    = O_F1 + 33554432;
  const size_t O_FG    = O_F2 + 67108864;
  const size_t O_F3    = O_FG + 2097152;
  const size_t O_END   = O_F3 + 134217728;
  // mamba-phase buffers alias the (dead) f3 region:
  const size_t O_XLN   = O_F3;
  const size_t O_UZ    = O_XLN + 3145728;
  const size_t O_UC    = O_UZ + 12582912;
  const size_t O_XBC   = O_UC + 6291456;
  const size_t O_DT    = O_XBC + 458752;
  const size_t O_YG    = O_DT + 6291456;
  const size_t O_T4    = O_F1;   // t4 (100663296 B) aliases f1+f2 exactly
  if (ws_size < O_END) return;

  int*   idx  = (int*)(w+O_IDX);
  float* cent = (float*)(w+O_CENT);
  float* pg   = (float*)(w+O_PG);
  float* a1 = (float*)(w+O_A1); float* b1 = (float*)(w+O_B1);
  float* a2 = (float*)(w+O_A2); float* b2 = (float*)(w+O_B2);
  float* pg1 = (float*)(w+O_PG1);
  float* pos = (float*)(w+O_POS);
  float* hb  = (float*)(w+O_H);
  float* res = (float*)(w+O_RES);
  float* f1 = (float*)(w+O_F1);
  float* f2 = (float*)(w+O_F2);
  float* fg = (float*)(w+O_FG);
  float* f3 = (float*)(w+O_F3);
  float* t4 = (float*)(w+O_T4);
  float* xln = (float*)(w+O_XLN);
  float* uzb = (float*)(w+O_UZ);
  float* ucb = (float*)(w+O_UC);
  float* xbc = (float*)(w+O_XBC);
  float* dtB = (float*)(w+O_DT);
  float* yg  = (float*)(w+O_YG);

  // ---- grouping ----
  fps_kernel<<<NBATCH, 64, 0, stream>>>(pts, idx);
  knn_kernel<<<NTOK, 256, 0, stream>>>(pts, idx, pg, cent);
  prep_kernel<<<1, 512, 0, stream>>>(bn1g,bn1b,bn1m,bn1v,e1b, bn2g,bn2b,bn2m,bn2v,e3b, a1,b1,a2,b2);

  // ---- point embedding ----
  e1_kernel<<<NROW*128/256, 256, 0, stream>>>(pg, e1w, a1, b1, f1);
  gemm_nt<1,false><<<dim3(2,512), 256, 0, stream>>>(f1, nullptr, e2w, e2b, nullptr, f2, NROW, 256, 128);
  fgpool_kernel<<<NTOK, 256, 0, stream>>>(f2, fg);
  gemm_nt<2,true ><<<dim3(4,512), 256, 0, stream>>>(f2, fg, e3w, a2, b2, f3, NROW, 512, 512);
  gemm_nt<1,false><<<dim3(3,512), 256, 0, stream>>>(f3, nullptr, e4w, e4b, nullptr, t4, NROW, 384, 512);
  p1_kernel<<<NTOK*128/256, 256, 0, stream>>>(cent, p1w, p1b, pg1);
  gemm_nt<1,false><<<dim3(3,16), 256, 0, stream>>>(pg1, nullptr, p2w, p2b, nullptr, pos, NTOK, 384, 128);
  tokpool_kernel<<<NTOK, 384, 0, stream>>>(t4, pos, hb);

  // ---- 12 mamba layers ----
  for (int i=0;i<NLAYER;i++){
    if (i==0) ln_kernel<false><<<NTOK,128,0,stream>>>(hb, res, xln, lng+(size_t)i*DMODEL, lnb+(size_t)i*DMODEL);
    else      ln_kernel<true ><<<NTOK,128,0,stream>>>(hb, res, xln, lng+(size_t)i*DMODEL, lnb+(size_t)i*DMODEL);
    gemm_nt<0,false><<<dim3(12,16),256,0,stream>>>(xln, nullptr, inw+(size_t)i*1536*DMODEL, nullptr,nullptr, uzb, NTOK, 1536, DMODEL);
    conv_kernel<<<NTOK*DINNER/256,256,0,stream>>>(uzb, convw+(size_t)i*DINNER*4, convb+(size_t)i*DINNER, ucb);
    gemm_nt<0,false><<<dim3(1,16),256,0,stream>>>(ucb, nullptr, xprojw+(size_t)i*56*DINNER, nullptr,nullptr, xbc, NTOK, 56, DINNER);
    dtproj_kernel<<<NTOK*DINNER/256,256,0,stream>>>(xbc, dtw+(size_t)i*DINNER*DTRANK, dtb+(size_t)i*DINNER, dtB);
    scan_kernel<<<NBATCH*3,256,0,stream>>>(ucb, dtB, xbc, uzb, Alog+(size_t)i*DINNER*DSTATE, Dp+(size_t)i*DINNER, yg);
    gemm_nt<0,false><<<dim3(3,16),256,0,stream>>>(yg, nullptr, outw+(size_t)i*DMODEL*DINNER, nullptr,nullptr, hb, NTOK, DMODEL, DINNER);
  }
  final_ln_kernel<<<NTOK,128,0,stream>>>(hb, res, nfg, nfb, out);
}

// Round 4
// 3705.769 us; speedup vs baseline: 1.6722x; 1.6722x over previous
//
#include <hip/hip_runtime.h>
#include <cstddef>
#include <cstdint>

#define NPTS   2048
#define NBATCH 16
#define NG     128
#define NM     32
#define DMODEL 384
#define DINNER 768
#define DSTATE 16
#define DTRANK 24
#define NLAYER 12
#define LEPS   1e-5f
#define NTOK   (NBATCH*NG)      /* 2048 tokens */
#define NROW   (NTOK*NM)        /* 65536 point rows */
#define FLTMAX 3.402823466e+38f

typedef __attribute__((ext_vector_type(8))) short bf16x8;
typedef __attribute__((ext_vector_type(4))) float f32x4;
typedef unsigned short ushort_t;

__device__ __forceinline__ unsigned short f2bf(float f){
  unsigned int u = __float_as_uint(f);
  unsigned int r = (u + 0x7FFFu + ((u>>16)&1u)) >> 16;
  return (unsigned short)r;
}
__device__ __forceinline__ float bf2f(unsigned short h){
  return __uint_as_float(((unsigned int)h)<<16);
}

// ---------------- FPS: one wave per batch, shuffle argmax reduce ----------------
__global__ __launch_bounds__(64) void fps_kernel(const float* __restrict__ pts, int* __restrict__ idx){
  const int b = blockIdx.x;
  const int lane = threadIdx.x;
  const float* P = pts + (size_t)b*NPTS*3;
  float px[32], py[32], pz[32], dmin[32];
  #pragma unroll
  for (int j=0;j<32;j++){
    int p = lane + j*64;
    px[j]=P[p*3+0]; py[j]=P[p*3+1]; pz[j]=P[p*3+2];
    dmin[j]=1e10f;
  }
  int cur = 0;
  if (lane==0) idx[b*NG+0] = 0;
  for (int it=1; it<NG; ++it){
    float lx = P[cur*3+0], ly = P[cur*3+1], lz = P[cur*3+2];
    float best = -1.0f; int bi = 0;
    #pragma unroll
    for (int j=0;j<32;j++){
      float dx=__fsub_rn(px[j],lx), dy=__fsub_rn(py[j],ly), dz=__fsub_rn(pz[j],lz);
      float d = __fadd_rn(__fadd_rn(__fmul_rn(dx,dx),__fmul_rn(dy,dy)),__fmul_rn(dz,dz));
      float dm = fminf(dmin[j], d);
      dmin[j]=dm;
      int p = lane + j*64;
      if (dm > best || (dm == best && p < bi)) { best = dm; bi = p; }
    }
    #pragma unroll
    for (int m=1;m<64;m<<=1){
      float ov = __shfl_xor(best, m);
      int   oi = __shfl_xor(bi, m);
      if (ov > best || (ov == best && oi < bi)){ best=ov; bi=oi; }
    }
    cur = __builtin_amdgcn_readfirstlane(bi);
    if (lane==0) idx[b*NG+it] = cur;
  }
}

// ---------------- kNN grouping ----------------
__global__ __launch_bounds__(256) void knn_kernel(const float* __restrict__ pts, const int* __restrict__ idx,
                                                  float* __restrict__ pg, float* __restrict__ centerb){
  __shared__ float sx[NPTS], sy[NPTS], sz[NPTS], sd[NPTS];
  __shared__ float rv[256]; __shared__ int ri[256];
  const int bid = blockIdx.x;
  const int b = bid >> 7;
  const int t = threadIdx.x;
  const float* P = pts + (size_t)b*NPTS*3;
  const int ci = idx[bid];
  const float cx = P[ci*3+0], cy = P[ci*3+1], cz = P[ci*3+2];
  const float cs = __fadd_rn(__fadd_rn(__fmul_rn(cx,cx),__fmul_rn(cy,cy)),__fmul_rn(cz,cz));
  for (int p=t; p<NPTS; p+=256){
    float x=P[p*3+0], y=P[p*3+1], z=P[p*3+2];
    float ps  = __fadd_rn(__fadd_rn(__fmul_rn(x,x),__fmul_rn(y,y)),__fmul_rn(z,z));
    float dot = __fadd_rn(__fadd_rn(__fmul_rn(cx,x),__fmul_rn(cy,y)),__fmul_rn(cz,z));
    float d = __fsub_rn(__fadd_rn(cs,ps), __fmul_rn(2.0f,dot));
    sx[p]=x; sy[p]=y; sz[p]=z; sd[p]=d;
  }
  if (t==0){ centerb[bid*3+0]=cx; centerb[bid*3+1]=cy; centerb[bid*3+2]=cz; }
  __syncthreads();
  for (int m=0;m<NM;m++){
    float bv = FLTMAX; int bp = NPTS;
    for (int p=t;p<NPTS;p+=256){
      float v = sd[p];
      if (v < bv || (v == bv && p < bp)){ bv=v; bp=p; }
    }
    rv[t]=bv; ri[t]=bp;
    __syncthreads();
    for (int s=128;s>0;s>>=1){
      if (t<s){
        float ov=rv[t+s]; int oi=ri[t+s];
        if (ov < rv[t] || (ov == rv[t] && oi < ri[t])){ rv[t]=ov; ri[t]=oi; }
      }
      __syncthreads();
    }
    if (t==0){
      int sel = ri[0];
      size_t orow = ((size_t)bid*NM + m)*3;
      pg[orow+0]=__fsub_rn(sx[sel],cx);
      pg[orow+1]=__fsub_rn(sy[sel],cy);
      pg[orow+2]=__fsub_rn(sz[sel],cz);
      sd[sel]=FLTMAX;
    }
    __syncthreads();
  }
}

// ---------------- folded BN coefficients ----------------
__global__ void prep_kernel(const float* bn1g, const float* bn1b, const float* bn1m, const float* bn1v, const float* e1b,
                            const float* bn2g, const float* bn2b, const float* bn2m, const float* bn2v, const float* e3b,
                            float* a1, float* b1, float* a2, float* b2){
  int t = threadIdx.x;
  if (t<128){ float a = bn1g[t]/sqrtf(bn1v[t]+LEPS); a1[t]=a; b1[t]=(e1b[t]-bn1m[t])*a+bn1b[t]; }
  if (t<512){ float a = bn2g[t]/sqrtf(bn2v[t]+LEPS); a2[t]=a; b2[t]=(e3b[t]-bn2m[t])*a+bn2b[t]; }
}

// ---------------- fp32 -> bf16 convert ----------------
__global__ __launch_bounds__(256) void cvt_kernel(const float* __restrict__ src, ushort_t* __restrict__ dst, int n){
  int i = blockIdx.x*256 + threadIdx.x;
  if (i < n) dst[i] = f2bf(src[i]);
}

// ---------------- tiny K=3 layers ----------------
__global__ __launch_bounds__(256) void e1_kernel(const float* __restrict__ pg, const float* __restrict__ w,
                                                 const float* __restrict__ a1, const float* __restrict__ b1,
                                                 ushort_t* __restrict__ f1b){
  int gid = blockIdx.x*256 + threadIdx.x;      // NROW*128
  int row = gid >> 7, c = gid & 127;
  float x = pg[(size_t)row*3+0], y = pg[(size_t)row*3+1], z = pg[(size_t)row*3+2];
  float v = x*w[c*3+0] + y*w[c*3+1] + z*w[c*3+2];
  f1b[gid] = f2bf(fmaxf(v*a1[c]+b1[c], 0.0f));
}

__global__ __launch_bounds__(256) void p1_kernel(const float* __restrict__ center, const float* __restrict__ w,
                                                 const float* __restrict__ bias, float* __restrict__ o){
  int gid = blockIdx.x*256 + threadIdx.x;      // NTOK*128
  int row = gid >> 7, c = gid & 127;
  float x = center[(size_t)row*3+0], y = center[(size_t)row*3+1], z = center[(size_t)row*3+2];
  float v = x*w[c*3+0]+y*w[c*3+1]+z*w[c*3+2] + bias[c];
  o[gid] = 0.5f*v*(1.0f+erff(v*0.70710678118654752f));  // exact gelu
}

// ---------------- bf16 MFMA GEMM: C[M,N] = A[M,K] @ W[N,K]^T ----------------
// 128x128 tile, BK=64, 4 waves (2x2), 16x16x32 bf16 MFMA, LDS rows padded to 72 bf16.
// EPI: 1 = +bias(P1); 2 = relu(acc*P1[n]+P2[n]). CONCAT: cols<256 from A2[row>>5], else A[row].
// Requires M%128==0, N%128==0, K%64==0 (and for CONCAT: K=512, A stride 256).
template<int EPI, bool CONCAT, bool OUTBF>
__global__ __launch_bounds__(256) void mfma_gemm(const ushort_t* __restrict__ A, const ushort_t* __restrict__ A2,
                                                 const ushort_t* __restrict__ W, const float* __restrict__ P1,
                                                 const float* __restrict__ P2, void* __restrict__ Cout,
                                                 int M, int N, int K){
  __shared__ short As[128*72];
  __shared__ short Ws[128*72];
  const int tid = threadIdx.x;
  const int bm = blockIdx.y*128, bn = blockIdx.x*128;
  const int lane = tid & 63, wid = tid >> 6;
  const int wm = (wid&1)*64, wn = (wid>>1)*64;
  f32x4 acc[4][4];
  #pragma unroll
  for (int i=0;i<4;i++)
    #pragma unroll
    for (int j=0;j<4;j++) acc[i][j] = (f32x4){0.f,0.f,0.f,0.f};

  for (int kt=0; kt<K; kt+=64){
    #pragma unroll
    for (int p=0;p<4;p++){
      int i = p*256 + tid;
      int row = i>>3, k8 = (i&7)*8;
      const ushort_t* src;
      if (CONCAT){
        int rg = bm+row;
        if (kt < 256) src = A2 + (size_t)(rg>>5)*256 + kt + k8;
        else          src = A  + (size_t)rg*256 + (kt-256) + k8;
      } else {
        src = A + (size_t)(bm+row)*K + kt + k8;
      }
      *(bf16x8*)(As + row*72 + k8) = *(const bf16x8*)src;
      *(bf16x8*)(Ws + row*72 + k8) = *(const bf16x8*)(W + (size_t)(bn+row)*K + kt + k8);
    }
    __syncthreads();
    #pragma unroll
    for (int kc=0;kc<2;kc++){
      bf16x8 af[4], bfr[4];
      #pragma unroll
      for (int mi=0;mi<4;mi++) af[mi]  = *(const bf16x8*)(As + (wm+mi*16+(lane&15))*72 + kc*32 + (lane>>4)*8);
      #pragma unroll
      for (int ni=0;ni<4;ni++) bfr[ni] = *(const bf16x8*)(Ws + (wn+ni*16+(lane&15))*72 + kc*32 + (lane>>4)*8);
      #pragma unroll
      for (int mi=0;mi<4;mi++)
        #pragma unroll
        for (int ni=0;ni<4;ni++)
          acc[mi][ni] = __builtin_amdgcn_mfma_f32_16x16x32_bf16(af[mi], bfr[ni], acc[mi][ni], 0,0,0);
    }
    __syncthreads();
  }
  // epilogue: D row=(lane>>4)*4+r, col=lane&15
  #pragma unroll
  for (int mi=0;mi<4;mi++){
    #pragma unroll
    for (int ni=0;ni<4;ni++){
      int col = bn + wn + ni*16 + (lane&15);
      #pragma unroll
      for (int r=0;r<4;r++){
        int row = bm + wm + mi*16 + (lane>>4)*4 + r;
        float v = acc[mi][ni][r];
        if (EPI==1) v += P1[col];
        else if (EPI==2) v = fmaxf(v*P1[col]+P2[col], 0.f);
        if (OUTBF) ((ushort_t*)Cout)[(size_t)row*N + col] = f2bf(v);
        else       ((float*)Cout)[(size_t)row*N + col] = v;
      }
    }
  }
}

// ---------------- fp32 GEMM, 64x64 tile (occupancy-friendly for small M/N) ----------------
// C[M,N] = A[M,K] @ W[N,K]^T (+bias). M%64==0, K%16==0, N arbitrary (guarded).
template<int EPI>
__global__ __launch_bounds__(256) void gemm64(const float* __restrict__ A, const float* __restrict__ W,
                                              const float* __restrict__ P1, float* __restrict__ C,
                                              int M, int N, int K){
  __shared__ float As[16][68];
  __shared__ float Ws[16][68];
  const int tid = threadIdx.x;
  const int bm = blockIdx.y*64, bn = blockIdx.x*64;
  const int tx = tid & 15, ty = tid >> 4;
  float acc[4][4];
  #pragma unroll
  for (int i=0;i<4;i++)
    #pragma unroll
    for (int j=0;j<4;j++) acc[i][j]=0.f;
  for (int kt=0; kt<K; kt+=16){
    int row = tid>>2, kq = (tid&3)*4;
    float4 va = *(const float4*)(A + (size_t)(bm+row)*K + kt + kq);
    As[kq+0][row]=va.x; As[kq+1][row]=va.y; As[kq+2][row]=va.z; As[kq+3][row]=va.w;
    float4 vw = make_float4(0.f,0.f,0.f,0.f);
    if (bn+row < N) vw = *(const float4*)(W + (size_t)(bn+row)*K + kt + kq);
    Ws[kq+0][row]=vw.x; Ws[kq+1][row]=vw.y; Ws[kq+2][row]=vw.z; Ws[kq+3][row]=vw.w;
    __syncthreads();
    #pragma unroll
    for (int k=0;k<16;k++){
      float a4[4], b4[4];
      *(float4*)&a4[0] = *(const float4*)&As[k][ty*4];
      *(float4*)&b4[0] = *(const float4*)&Ws[k][tx*4];
      #pragma unroll
      for (int i=0;i<4;i++)
        #pragma unroll
        for (int j=0;j<4;j++) acc[i][j] += a4[i]*b4[j];
    }
    __syncthreads();
  }
  #pragma unroll
  for (int i=0;i<4;i++){
    int rg = bm + ty*4 + i;
    #pragma unroll
    for (int j=0;j<4;j++){
      int n = bn + tx*4 + j;
      if (n < N){
        float v = acc[i][j];
        if (EPI==1) v += P1[n];
        C[(size_t)rg*N + n] = v;
      }
    }
  }
}

// ---------------- max-pools ----------------
__global__ __launch_bounds__(256) void fgpool_kernel(const ushort_t* __restrict__ f2b, ushort_t* __restrict__ fgb){
  int g = blockIdx.x, c = threadIdx.x;
  float m = -FLTMAX;
  for (int mm=0;mm<NM;mm++) m = fmaxf(m, bf2f(f2b[((size_t)(g*NM+mm))*256 + c]));
  fgb[(size_t)g*256+c]=f2bf(m);   // exact: m is a bf16-representable value
}
__global__ __launch_bounds__(384) void tokpool_kernel(const float* __restrict__ t4, const float* __restrict__ pos,
                                                      float* __restrict__ h){
  int g = blockIdx.x, c = threadIdx.x;
  float m = -FLTMAX;
  for (int mm=0;mm<NM;mm++) m = fmaxf(m, t4[((size_t)(g*NM+mm))*DMODEL + c]);
  h[(size_t)g*DMODEL+c] = m + pos[(size_t)g*DMODEL+c];
}

// ---------------- LayerNorm (+residual update) ----------------
template<bool ADD>
__global__ __launch_bounds__(128) void ln_kernel(const float* __restrict__ hbuf, float* __restrict__ res,
                                                 float* __restrict__ xln, const float* __restrict__ gamma,
                                                 const float* __restrict__ beta){
  __shared__ float s[128];
  int row = blockIdx.x, t = threadIdx.x;
  const float* hr = hbuf + (size_t)row*DMODEL;
  float* rr = res + (size_t)row*DMODEL;
  float v[3]; float lsum=0.f;
  #pragma unroll
  for (int i=0;i<3;i++){ int c=t+i*128; float x=hr[c]; if(ADD) x+=rr[c]; v[i]=x; lsum+=x; }
  #pragma unroll
  for (int i=0;i<3;i++) rr[t+i*128]=v[i];
  s[t]=lsum; __syncthreads();
  for (int o=64;o>0;o>>=1){ if(t<o) s[t]+=s[t+o]; __syncthreads(); }
  float mean = s[0]*(1.0f/384.0f);
  __syncthreads();
  float l2=0.f;
  #pragma unroll
  for (int i=0;i<3;i++){ float dmu=v[i]-mean; l2+=dmu*dmu; }
  s[t]=l2; __syncthreads();
  for (int o=64;o>0;o>>=1){ if(t<o) s[t]+=s[t+o]; __syncthreads(); }
  float var = s[0]*(1.0f/384.0f);
  float rs = 1.0f/sqrtf(var+LEPS);
  #pragma unroll
  for (int i=0;i<3;i++){ int c=t+i*128; xln[(size_t)row*DMODEL+c] = (v[i]-mean)*rs*gamma[c]+beta[c]; }
}

__global__ __launch_bounds__(128) void final_ln_kernel(const float* __restrict__ hbuf, const float* __restrict__ res,
                                                       const float* __restrict__ gamma, const float* __restrict__ beta,
                                                       float* __restrict__ out){
  __shared__ float s[128];
  int row = blockIdx.x, t = threadIdx.x;
  const float* hr = hbuf + (size_t)row*DMODEL;
  const float* rr = res + (size_t)row*DMODEL;
  float v[3]; float lsum=0.f;
  #pragma unroll
  for (int i=0;i<3;i++){ int c=t+i*128; float x=hr[c]+rr[c]; v[i]=x; lsum+=x; }
  s[t]=lsum; __syncthreads();
  for (int o=64;o>0;o>>=1){ if(t<o) s[t]+=s[t+o]; __syncthreads(); }
  float mean = s[0]*(1.0f/384.0f);
  __syncthreads();
  float l2=0.f;
  #pragma unroll
  for (int i=0;i<3;i++){ float dmu=v[i]-mean; l2+=dmu*dmu; }
  s[t]=l2; __syncthreads();
  for (int o=64;o>0;o>>=1){ if(t<o) s[t]+=s[t+o]; __syncthreads(); }
  float var = s[0]*(1.0f/384.0f);
  float rs = 1.0f/sqrtf(var+LEPS);
  #pragma unroll
  for (int i=0;i<3;i++){ int c=t+i*128; out[(size_t)row*DMODEL+c] = (v[i]-mean)*rs*gamma[c]+beta[c]; }
}

// ---------------- depthwise causal conv(k=4) + silu ----------------
__global__ __launch_bounds__(256) void conv_kernel(const float* __restrict__ uz, const float* __restrict__ cw,
                                                   const float* __restrict__ cb, float* __restrict__ uc){
  int gid = blockIdx.x*256 + threadIdx.x;  // NTOK*DINNER
  int d = gid % DINNER;
  int rl = gid / DINNER;
  int l = rl & (NG-1);
  float acc = cb[d];
  #pragma unroll
  for (int k=0;k<4;k++){
    int l2 = l-3+k;
    if (l2 >= 0) acc += uz[(size_t)(rl-3+k)*1536 + d]*cw[d*4+k];
  }
  uc[gid] = acc/(1.0f+__expf(-acc));
}

// ---------------- dt = softplus(xbc[:, :24] @ dtw^T + dtb) ----------------
__global__ __launch_bounds__(256) void dtproj_kernel(const float* __restrict__ xbc, const float* __restrict__ dtw,
                                                     const float* __restrict__ dtb, float* __restrict__ dt){
  int gid = blockIdx.x*256 + threadIdx.x;  // NTOK*DINNER
  int d = gid % DINNER;
  int r = gid / DINNER;
  float acc = dtb[d];
  const float* xr = xbc + (size_t)r*56;
  #pragma unroll
  for (int j=0;j<DTRANK;j++) acc += xr[j]*dtw[d*DTRANK+j];
  dt[gid] = (acc > 20.0f) ? acc : log1pf(__expf(acc));
}

// ---------------- SSM scan + skip + gating ----------------
__global__ __launch_bounds__(256) void scan_kernel(const float* __restrict__ uc, const float* __restrict__ dt,
                                                   const float* __restrict__ xbc, const float* __restrict__ uz,
                                                   const float* __restrict__ Alog, const float* __restrict__ Dp,
                                                   float* __restrict__ yg){
  int blk = blockIdx.x;          // NBATCH*3
  int b = blk/3, chunk = blk%3;
  int d = chunk*256 + threadIdx.x;
  float a[DSTATE];
  #pragma unroll
  for (int s=0;s<DSTATE;s++) a[s] = -expf(Alog[(size_t)d*DSTATE+s]);
  float D_ = Dp[d];
  float h[DSTATE];
  #pragma unroll
  for (int s=0;s<DSTATE;s++) h[s]=0.f;
  for (int l=0;l<NG;l++){
    int r = b*NG + l;
    float dtv = dt[(size_t)r*DINNER + d];
    float uv  = uc[(size_t)r*DINNER + d];
    float du = dtv*uv;
    const float* xb = xbc + (size_t)r*56;
    float4 B0 = *(const float4*)(xb+24), B1 = *(const float4*)(xb+28);
    float4 B2 = *(const float4*)(xb+32), B3 = *(const float4*)(xb+36);
    float4 C0 = *(const float4*)(xb+40), C1 = *(const float4*)(xb+44);
    float4 C2 = *(const float4*)(xb+48), C3 = *(const float4*)(xb+52);
    float Bs[16] = {B0.x,B0.y,B0.z,B0.w,B1.x,B1.y,B1.z,B1.w,B2.x,B2.y,B2.z,B2.w,B3.x,B3.y,B3.z,B3.w};
    float Cs[16] = {C0.x,C0.y,C0.z,C0.w,C1.x,C1.y,C1.z,C1.w,C2.x,C2.y,C2.z,C2.w,C3.x,C3.y,C3.z,C3.w};
    float y = 0.f;
    #pragma unroll
    for (int s=0;s<DSTATE;s++){
      float dA = __expf(dtv*a[s]);
      h[s] = dA*h[s] + du*Bs[s];
      y += h[s]*Cs[s];
    }
    float zv = uz[(size_t)r*1536 + DINNER + d];
    float sg = zv/(1.0f+__expf(-zv));
    yg[(size_t)r*DINNER + d] = (y + uv*D_)*sg;
  }
}

// ---------------- launch ----------------
extern "C" void kernel_launch(void* const* d_in, const int* in_sizes, int n_in,
                              void* d_out, int out_size, void* d_ws, size_t ws_size,
                              hipStream_t stream){
  const float* pts   = (const float*)d_in[0];
  const float* e1w   = (const float*)d_in[1];
  const float* e1b   = (const float*)d_in[2];
  const float* bn1g  = (const float*)d_in[3];
  const float* bn1b  = (const float*)d_in[4];
  const float* bn1m  = (const float*)d_in[5];
  const float* bn1v  = (const float*)d_in[6];
  const float* e2w   = (const float*)d_in[7];
  const float* e2b   = (const float*)d_in[8];
  const float* e3w   = (const float*)d_in[9];
  const float* e3b   = (const float*)d_in[10];
  const float* bn2g  = (const float*)d_in[11];
  const float* bn2b  = (const float*)d_in[12];
  const float* bn2m  = (const float*)d_in[13];
  const float* bn2v  = (const float*)d_in[14];
  const float* e4w   = (const float*)d_in[15];
  const float* e4b   = (const float*)d_in[16];
  const float* p1w   = (const float*)d_in[17];
  const float* p1b   = (const float*)d_in[18];
  const float* p2w   = (const float*)d_in[19];
  const float* p2b   = (const float*)d_in[20];
  const float* lng   = (const float*)d_in[21];
  const float* lnb   = (const float*)d_in[22];
  const float* inw   = (const float*)d_in[23];
  const float* convw = (const float*)d_in[24];
  const float* convb = (const float*)d_in[25];
  const float* xprojw= (const float*)d_in[26];
  const float* dtw   = (const float*)d_in[27];
  const float* dtb   = (const float*)d_in[28];
  const float* Alog  = (const float*)d_in[29];
  const float* Dp    = (const float*)d_in[30];
  const float* outw  = (const float*)d_in[31];
  const float* nfg   = (const float*)d_in[32];
  const float* nfb   = (const float*)d_in[33];
  float* out = (float*)d_out;

  char* w = (char*)d_ws;
  const size_t O_IDX   = 0;
  const size_t O_CENT  = 8192;
  const size_t O_PG    = 32768;
  const size_t O_A1    = 819200;
  const size_t O_B1    = 819712;
  const size_t O_A2    = 820224;
  const size_t O_B2    = 822272;
  const size_t O_PG1   = 824320;
  const size_t O_POS   = 1872896;
  const size_t O_H     = 5018624;
  const size_t O_RES   = 8164352;
  const size_t O_E2WB  = 11310080;
  const size_t O_E3WB  = 11375616;
  const size_t O_E4WB  = 11899904;
  const size_t O_F3B   = 12293120;               // 64 MB (bf16 f3)
  const size_t O_F1B   = 79401984;               // 16 MB
  const size_t O_F2B   = 96179200;               // 32 MB
  const size_t O_FGB   = 129733632;              // 1 MB
  const size_t O_T4    = O_F1B;                  // t4 fp32 (100663296 B) over dead f1b/f2b/fgb
  const size_t O_END   = O_T4 + 100663296;       // 180065280
  // mamba-phase buffers alias the (dead) f3b region:
  const size_t O_XLN   = O_F3B;
  const size_t O_UZ    = O_XLN + 3145728;
  const size_t O_UC    = O_UZ + 12582912;
  const size_t O_XBC   = O_UC + 6291456;
  const size_t O_DT    = O_XBC + 458752;
  const size_t O_YG    = O_DT + 6291456;
  if (ws_size < O_END) return;

  int*   idx  = (int*)(w+O_IDX);
  float* cent = (float*)(w+O_CENT);
  float* pg   = (float*)(w+O_PG);
  float* a1 = (float*)(w+O_A1); float* b1 = (float*)(w+O_B1);
  float* a2 = (float*)(w+O_A2); float* b2 = (float*)(w+O_B2);
  float* pg1 = (float*)(w+O_PG1);
  float* pos = (float*)(w+O_POS);
  float* hb  = (float*)(w+O_H);
  float* res = (float*)(w+O_RES);
  ushort_t* e2wb = (ushort_t*)(w+O_E2WB);
  ushort_t* e3wb = (ushort_t*)(w+O_E3WB);
  ushort_t* e4wb = (ushort_t*)(w+O_E4WB);
  ushort_t* f1b = (ushort_t*)(w+O_F1B);
  ushort_t* f2b = (ushort_t*)(w+O_F2B);
  ushort_t* fgb = (ushort_t*)(w+O_FGB);
  ushort_t* f3b = (ushort_t*)(w+O_F3B);
  float* t4  = (float*)(w+O_T4);
  float* xln = (float*)(w+O_XLN);
  float* uzb = (float*)(w+O_UZ);
  float* ucb = (float*)(w+O_UC);
  float* xbc = (float*)(w+O_XBC);
  float* dtB = (float*)(w+O_DT);
  float* yg  = (float*)(w+O_YG);

  // ---- grouping ----
  fps_kernel<<<NBATCH, 64, 0, stream>>>(pts, idx);
  knn_kernel<<<NTOK, 256, 0, stream>>>(pts, idx, pg, cent);
  prep_kernel<<<1, 512, 0, stream>>>(bn1g,bn1b,bn1m,bn1v,e1b, bn2g,bn2b,bn2m,bn2v,e3b, a1,b1,a2,b2);
  cvt_kernel<<<(256*128+255)/256, 256, 0, stream>>>(e2w, e2wb, 256*128);
  cvt_kernel<<<(512*512+255)/256, 256, 0, stream>>>(e3w, e3wb, 512*512);
  cvt_kernel<<<(384*512+255)/256, 256, 0, stream>>>(e4w, e4wb, 384*512);

  // ---- point embedding (bf16 MFMA) ----
  e1_kernel<<<NROW*128/256, 256, 0, stream>>>(pg, e1w, a1, b1, f1b);
  mfma_gemm<1,false,true ><<<dim3(2,512), 256, 0, stream>>>(f1b, nullptr, e2wb, e2b, nullptr, f2b, NROW, 256, 128);
  fgpool_kernel<<<NTOK, 256, 0, stream>>>(f2b, fgb);
  mfma_gemm<2,true ,true ><<<dim3(4,512), 256, 0, stream>>>(f2b, fgb, e3wb, a2, b2, f3b, NROW, 512, 512);
  mfma_gemm<1,false,false><<<dim3(3,512), 256, 0, stream>>>(f3b, nullptr, e4wb, e4b, nullptr, t4, NROW, 384, 512);
  p1_kernel<<<NTOK*128/256, 256, 0, stream>>>(cent, p1w, p1b, pg1);
  gemm64<1><<<dim3(6,32), 256, 0, stream>>>(pg1, p2w, p2b, pos, NTOK, 384, 128);
  tokpool_kernel<<<NTOK, 384, 0, stream>>>(t4, pos, hb);

  // ---- 12 mamba layers (fp32) ----
  for (int i=0;i<NLAYER;i++){
    if (i==0) ln_kernel<false><<<NTOK,128,0,stream>>>(hb, res, xln, lng+(size_t)i*DMODEL, lnb+(size_t)i*DMODEL);
    else      ln_kernel<true ><<<NTOK,128,0,stream>>>(hb, res, xln, lng+(size_t)i*DMODEL, lnb+(size_t)i*DMODEL);
    gemm64<0><<<dim3(24,32),256,0,stream>>>(xln, inw+(size_t)i*1536*DMODEL, nullptr, uzb, NTOK, 1536, DMODEL);
    conv_kernel<<<NTOK*DINNER/256,256,0,stream>>>(uzb, convw+(size_t)i*DINNER*4, convb+(size_t)i*DINNER, ucb);
    gemm64<0><<<dim3(1,32),256,0,stream>>>(ucb, xprojw+(size_t)i*56*DINNER, nullptr, xbc, NTOK, 56, DINNER);
    dtproj_kernel<<<NTOK*DINNER/256,256,0,stream>>>(xbc, dtw+(size_t)i*DINNER*DTRANK, dtb+(size_t)i*DINNER, dtB);
    scan_kernel<<<NBATCH*3,256,0,stream>>>(ucb, dtB, xbc, uzb, Alog+(size_t)i*DINNER*DSTATE, Dp+(size_t)i*DINNER, yg);
    gemm64<0><<<dim3(6,32),256,0,stream>>>(yg, outw+(size_t)i*DMODEL*DINNER, nullptr, hb, NTOK, DMODEL, DINNER);
  }
  final_ln_kernel<<<NTOK,128,0,stream>>>(hb, res, nfg, nfb, out);
}

// Round 5
// 3105.441 us; speedup vs baseline: 1.9955x; 1.1933x over previous
//
#include <hip/hip_runtime.h>
#include <cstddef>
#include <cstdint>

#define NPTS   2048
#define NBATCH 16
#define NG     128
#define NM     32
#define DMODEL 384
#define DINNER 768
#define DSTATE 16
#define DTRANK 24
#define NLAYER 12
#define LEPS   1e-5f
#define NTOK   (NBATCH*NG)      /* 2048 tokens */
#define NROW   (NTOK*NM)        /* 65536 point rows */
#define FLTMAX 3.402823466e+38f

typedef __attribute__((ext_vector_type(8))) short bf16x8;
typedef __attribute__((ext_vector_type(4))) float f32x4;
typedef unsigned short ushort_t;

__device__ __forceinline__ unsigned short f2bf(float f){
  unsigned int u = __float_as_uint(f);
  unsigned int r = (u + 0x7FFFu + ((u>>16)&1u)) >> 16;
  return (unsigned short)r;
}
__device__ __forceinline__ float bf2f(unsigned short h){
  return __uint_as_float(((unsigned int)h)<<16);
}

// ---------------- FPS: 256 threads/block, points in LDS (no VGPR spill) ----------------
// Matches jnp semantics exactly: _rn ops in numpy association order, dmin=min accum,
// argmax tie-break = lowest index.
__global__ __launch_bounds__(256) void fps_kernel(const float* __restrict__ pts, int* __restrict__ idx){
  __shared__ float sx[NPTS], sy[NPTS], sz[NPTS];
  __shared__ float wbv[4]; __shared__ int wbi4[4];
  const int b = blockIdx.x, t = threadIdx.x;
  const float* P = pts + (size_t)b*NPTS*3;
  for (int p=t; p<NPTS; p+=256){ sx[p]=P[p*3+0]; sy[p]=P[p*3+1]; sz[p]=P[p*3+2]; }
  float dmin[8];
  #pragma unroll
  for (int j=0;j<8;j++) dmin[j]=1e10f;
  __syncthreads();
  int cur = 0;
  if (t==0) idx[b*NG+0] = 0;
  for (int it=1; it<NG; ++it){
    float lx=sx[cur], ly=sy[cur], lz=sz[cur];
    float best = -1.0f; int bi = 0;
    #pragma unroll
    for (int j=0;j<8;j++){
      int p = t + j*256;
      float dx=__fsub_rn(sx[p],lx), dy=__fsub_rn(sy[p],ly), dz=__fsub_rn(sz[p],lz);
      float dd = __fadd_rn(__fadd_rn(__fmul_rn(dx,dx),__fmul_rn(dy,dy)),__fmul_rn(dz,dz));
      float dm = fminf(dmin[j], dd);
      dmin[j]=dm;
      if (dm > best || (dm == best && p < bi)) { best = dm; bi = p; }
    }
    #pragma unroll
    for (int m=1;m<64;m<<=1){
      float ov = __shfl_xor(best, m);
      int   oi = __shfl_xor(bi, m);
      if (ov > best || (ov == best && oi < bi)){ best=ov; bi=oi; }
    }
    if ((t&63)==0){ wbv[t>>6]=best; wbi4[t>>6]=bi; }
    __syncthreads();
    float b0=wbv[0]; int i0=wbi4[0];
    #pragma unroll
    for (int k2=1;k2<4;k2++){
      float ov=wbv[k2]; int oi=wbi4[k2];
      if (ov > b0 || (ov == b0 && oi < i0)){ b0=ov; i0=oi; }
    }
    cur = i0;
    if (t==0) idx[b*NG+it] = cur;
    __syncthreads();
  }
}

// ---------------- kNN grouping ----------------
__global__ __launch_bounds__(256) void knn_kernel(const float* __restrict__ pts, const int* __restrict__ idx,
                                                  float* __restrict__ pg, float* __restrict__ centerb){
  __shared__ float sx[NPTS], sy[NPTS], sz[NPTS], sd[NPTS];
  __shared__ float rv[256]; __shared__ int ri[256];
  const int bid = blockIdx.x;
  const int b = bid >> 7;
  const int t = threadIdx.x;
  const float* P = pts + (size_t)b*NPTS*3;
  const int ci = idx[bid];
  const float cx = P[ci*3+0], cy = P[ci*3+1], cz = P[ci*3+2];
  const float cs = __fadd_rn(__fadd_rn(__fmul_rn(cx,cx),__fmul_rn(cy,cy)),__fmul_rn(cz,cz));
  for (int p=t; p<NPTS; p+=256){
    float x=P[p*3+0], y=P[p*3+1], z=P[p*3+2];
    float ps  = __fadd_rn(__fadd_rn(__fmul_rn(x,x),__fmul_rn(y,y)),__fmul_rn(z,z));
    float dot = __fadd_rn(__fadd_rn(__fmul_rn(cx,x),__fmul_rn(cy,y)),__fmul_rn(cz,z));
    float d = __fsub_rn(__fadd_rn(cs,ps), __fmul_rn(2.0f,dot));
    sx[p]=x; sy[p]=y; sz[p]=z; sd[p]=d;
  }
  if (t==0){ centerb[bid*3+0]=cx; centerb[bid*3+1]=cy; centerb[bid*3+2]=cz; }
  __syncthreads();
  for (int m=0;m<NM;m++){
    float bv = FLTMAX; int bp = NPTS;
    for (int p=t;p<NPTS;p+=256){
      float v = sd[p];
      if (v < bv || (v == bv && p < bp)){ bv=v; bp=p; }
    }
    rv[t]=bv; ri[t]=bp;
    __syncthreads();
    for (int s=128;s>0;s>>=1){
      if (t<s){
        float ov=rv[t+s]; int oi=ri[t+s];
        if (ov < rv[t] || (ov == rv[t] && oi < ri[t])){ rv[t]=ov; ri[t]=oi; }
      }
      __syncthreads();
    }
    if (t==0){
      int sel = ri[0];
      size_t orow = ((size_t)bid*NM + m)*3;
      pg[orow+0]=__fsub_rn(sx[sel],cx);
      pg[orow+1]=__fsub_rn(sy[sel],cy);
      pg[orow+2]=__fsub_rn(sz[sel],cz);
      sd[sel]=FLTMAX;
    }
    __syncthreads();
  }
}

// ---------------- folded BN coefficients ----------------
__global__ void prep_kernel(const float* bn1g, const float* bn1b, const float* bn1m, const float* bn1v, const float* e1b,
                            const float* bn2g, const float* bn2b, const float* bn2m, const float* bn2v, const float* e3b,
                            float* a1, float* b1, float* a2, float* b2){
  int t = threadIdx.x;
  if (t<128){ float a = bn1g[t]/sqrtf(bn1v[t]+LEPS); a1[t]=a; b1[t]=(e1b[t]-bn1m[t])*a+bn1b[t]; }
  if (t<512){ float a = bn2g[t]/sqrtf(bn2v[t]+LEPS); a2[t]=a; b2[t]=(e3b[t]-bn2m[t])*a+bn2b[t]; }
}

// ---------------- fp32 -> bf16 convert ----------------
__global__ __launch_bounds__(256) void cvt_kernel(const float* __restrict__ src, ushort_t* __restrict__ dst, int n){
  int i = blockIdx.x*256 + threadIdx.x;
  if (i < n) dst[i] = f2bf(src[i]);
}

// ---------------- tiny K=3 layers ----------------
__global__ __launch_bounds__(256) void e1_kernel(const float* __restrict__ pg, const float* __restrict__ w,
                                                 const float* __restrict__ a1, const float* __restrict__ b1,
                                                 ushort_t* __restrict__ f1b){
  int gid = blockIdx.x*256 + threadIdx.x;      // NROW*128
  int row = gid >> 7, c = gid & 127;
  float x = pg[(size_t)row*3+0], y = pg[(size_t)row*3+1], z = pg[(size_t)row*3+2];
  float v = x*w[c*3+0] + y*w[c*3+1] + z*w[c*3+2];
  f1b[gid] = f2bf(fmaxf(v*a1[c]+b1[c], 0.0f));
}

__global__ __launch_bounds__(256) void p1_kernel(const float* __restrict__ center, const float* __restrict__ w,
                                                 const float* __restrict__ bias, float* __restrict__ o){
  int gid = blockIdx.x*256 + threadIdx.x;      // NTOK*128
  int row = gid >> 7, c = gid & 127;
  float x = center[(size_t)row*3+0], y = center[(size_t)row*3+1], z = center[(size_t)row*3+2];
  float v = x*w[c*3+0]+y*w[c*3+1]+z*w[c*3+2] + bias[c];
  o[gid] = 0.5f*v*(1.0f+erff(v*0.70710678118654752f));  // exact gelu
}

// ---------------- bf16 MFMA GEMM: C[M,N] = A[M,K] @ W[N,K]^T ----------------
// 128x128 tile, BK=64, 4 waves (2x2), 16x16x32 bf16 MFMA, LDS rows padded to 72 bf16.
// EPI: 0=none, 1=+bias(P1), 2=relu(acc*P1[n]+P2[n]). CONCAT: cols<256 from A2[row>>5], else A[row].
// Requires M%128==0, N%128==0, K%64==0.
template<int EPI, bool CONCAT, bool OUTBF>
__global__ __launch_bounds__(256) void mfma_gemm(const ushort_t* __restrict__ A, const ushort_t* __restrict__ A2,
                                                 const ushort_t* __restrict__ W, const float* __restrict__ P1,
                                                 const float* __restrict__ P2, void* __restrict__ Cout,
                                                 int M, int N, int K){
  __shared__ short As[128*72];
  __shared__ short Ws[128*72];
  const int tid = threadIdx.x;
  const int bm = blockIdx.y*128, bn = blockIdx.x*128;
  const int lane = tid & 63, wid = tid >> 6;
  const int wm = (wid&1)*64, wn = (wid>>1)*64;
  f32x4 acc[4][4];
  #pragma unroll
  for (int i=0;i<4;i++)
    #pragma unroll
    for (int j=0;j<4;j++) acc[i][j] = (f32x4){0.f,0.f,0.f,0.f};

  for (int kt=0; kt<K; kt+=64){
    #pragma unroll
    for (int p=0;p<4;p++){
      int i = p*256 + tid;
      int row = i>>3, k8 = (i&7)*8;
      const ushort_t* src;
      if (CONCAT){
        int rg = bm+row;
        if (kt < 256) src = A2 + (size_t)(rg>>5)*256 + kt + k8;
        else          src = A  + (size_t)rg*256 + (kt-256) + k8;
      } else {
        src = A + (size_t)(bm+row)*K + kt + k8;
      }
      *(bf16x8*)(As + row*72 + k8) = *(const bf16x8*)src;
      *(bf16x8*)(Ws + row*72 + k8) = *(const bf16x8*)(W + (size_t)(bn+row)*K + kt + k8);
    }
    __syncthreads();
    #pragma unroll
    for (int kc=0;kc<2;kc++){
      bf16x8 af[4], bfr[4];
      #pragma unroll
      for (int mi=0;mi<4;mi++) af[mi]  = *(const bf16x8*)(As + (wm+mi*16+(lane&15))*72 + kc*32 + (lane>>4)*8);
      #pragma unroll
      for (int ni=0;ni<4;ni++) bfr[ni] = *(const bf16x8*)(Ws + (wn+ni*16+(lane&15))*72 + kc*32 + (lane>>4)*8);
      #pragma unroll
      for (int mi=0;mi<4;mi++)
        #pragma unroll
        for (int ni=0;ni<4;ni++)
          acc[mi][ni] = __builtin_amdgcn_mfma_f32_16x16x32_bf16(af[mi], bfr[ni], acc[mi][ni], 0,0,0);
    }
    __syncthreads();
  }
  // epilogue: D row=(lane>>4)*4+r, col=lane&15
  #pragma unroll
  for (int mi=0;mi<4;mi++){
    #pragma unroll
    for (int ni=0;ni<4;ni++){
      int col = bn + wn + ni*16 + (lane&15);
      #pragma unroll
      for (int r=0;r<4;r++){
        int row = bm + wm + mi*16 + (lane>>4)*4 + r;
        float v = acc[mi][ni][r];
        if (EPI==1) v += P1[col];
        else if (EPI==2) v = fmaxf(v*P1[col]+P2[col], 0.f);
        if (OUTBF) ((ushort_t*)Cout)[(size_t)row*N + col] = f2bf(v);
        else       ((float*)Cout)[(size_t)row*N + col] = v;
      }
    }
  }
}

// ---------------- fp32 GEMM, 64x64 tile ----------------
template<int EPI>
__global__ __launch_bounds__(256) void gemm64(const float* __restrict__ A, const float* __restrict__ W,
                                              const float* __restrict__ P1, float* __restrict__ C,
                                              int M, int N, int K){
  __shared__ float As[16][68];
  __shared__ float Ws[16][68];
  const int tid = threadIdx.x;
  const int bm = blockIdx.y*64, bn = blockIdx.x*64;
  const int tx = tid & 15, ty = tid >> 4;
  float acc[4][4];
  #pragma unroll
  for (int i=0;i<4;i++)
    #pragma unroll
    for (int j=0;j<4;j++) acc[i][j]=0.f;
  for (int kt=0; kt<K; kt+=16){
    int row = tid>>2, kq = (tid&3)*4;
    float4 va = *(const float4*)(A + (size_t)(bm+row)*K + kt + kq);
    As[kq+0][row]=va.x; As[kq+1][row]=va.y; As[kq+2][row]=va.z; As[kq+3][row]=va.w;
    float4 vw = make_float4(0.f,0.f,0.f,0.f);
    if (bn+row < N) vw = *(const float4*)(W + (size_t)(bn+row)*K + kt + kq);
    Ws[kq+0][row]=vw.x; Ws[kq+1][row]=vw.y; Ws[kq+2][row]=vw.z; Ws[kq+3][row]=vw.w;
    __syncthreads();
    #pragma unroll
    for (int k=0;k<16;k++){
      float a4[4], b4[4];
      *(float4*)&a4[0] = *(const float4*)&As[k][ty*4];
      *(float4*)&b4[0] = *(const float4*)&Ws[k][tx*4];
      #pragma unroll
      for (int i=0;i<4;i++)
        #pragma unroll
        for (int j=0;j<4;j++) acc[i][j] += a4[i]*b4[j];
    }
    __syncthreads();
  }
  #pragma unroll
  for (int i=0;i<4;i++){
    int rg = bm + ty*4 + i;
    #pragma unroll
    for (int j=0;j<4;j++){
      int n = bn + tx*4 + j;
      if (n < N){
        float v = acc[i][j];
        if (EPI==1) v += P1[n];
        C[(size_t)rg*N + n] = v;
      }
    }
  }
}

// ---------------- max-pools ----------------
__global__ __launch_bounds__(256) void fgpool_kernel(const ushort_t* __restrict__ f2b, ushort_t* __restrict__ fgb){
  int g = blockIdx.x, c = threadIdx.x;
  float m = -FLTMAX;
  for (int mm=0;mm<NM;mm++) m = fmaxf(m, bf2f(f2b[((size_t)(g*NM+mm))*256 + c]));
  fgb[(size_t)g*256+c]=f2bf(m);   // exact: m is bf16-representable
}
__global__ __launch_bounds__(384) void tokpool_kernel(const ushort_t* __restrict__ t4b, const float* __restrict__ pos,
                                                      float* __restrict__ h){
  int g = blockIdx.x, c = threadIdx.x;
  float m = -FLTMAX;
  for (int mm=0;mm<NM;mm++) m = fmaxf(m, bf2f(t4b[((size_t)(g*NM+mm))*DMODEL + c]));
  h[(size_t)g*DMODEL+c] = m + pos[(size_t)g*DMODEL+c];
}

// ---------------- LayerNorm (+residual update), bf16 xln out ----------------
template<bool ADD>
__global__ __launch_bounds__(128) void ln_kernel(const float* __restrict__ hbuf, float* __restrict__ res,
                                                 ushort_t* __restrict__ xlnb, const float* __restrict__ gamma,
                                                 const float* __restrict__ beta){
  __shared__ float s[128];
  int row = blockIdx.x, t = threadIdx.x;
  const float* hr = hbuf + (size_t)row*DMODEL;
  float* rr = res + (size_t)row*DMODEL;
  float v[3]; float lsum=0.f;
  #pragma unroll
  for (int i=0;i<3;i++){ int c=t+i*128; float x=hr[c]; if(ADD) x+=rr[c]; v[i]=x; lsum+=x; }
  #pragma unroll
  for (int i=0;i<3;i++) rr[t+i*128]=v[i];
  s[t]=lsum; __syncthreads();
  for (int o=64;o>0;o>>=1){ if(t<o) s[t]+=s[t+o]; __syncthreads(); }
  float mean = s[0]*(1.0f/384.0f);
  __syncthreads();
  float l2=0.f;
  #pragma unroll
  for (int i=0;i<3;i++){ float dmu=v[i]-mean; l2+=dmu*dmu; }
  s[t]=l2; __syncthreads();
  for (int o=64;o>0;o>>=1){ if(t<o) s[t]+=s[t+o]; __syncthreads(); }
  float var = s[0]*(1.0f/384.0f);
  float rs = 1.0f/sqrtf(var+LEPS);
  #pragma unroll
  for (int i=0;i<3;i++){ int c=t+i*128; xlnb[(size_t)row*DMODEL+c] = f2bf((v[i]-mean)*rs*gamma[c]+beta[c]); }
}

__global__ __launch_bounds__(128) void final_ln_kernel(const float* __restrict__ hbuf, const float* __restrict__ res,
                                                       const float* __restrict__ gamma, const float* __restrict__ beta,
                                                       float* __restrict__ out){
  __shared__ float s[128];
  int row = blockIdx.x, t = threadIdx.x;
  const float* hr = hbuf + (size_t)row*DMODEL;
  const float* rr = res + (size_t)row*DMODEL;
  float v[3]; float lsum=0.f;
  #pragma unroll
  for (int i=0;i<3;i++){ int c=t+i*128; float x=hr[c]+rr[c]; v[i]=x; lsum+=x; }
  s[t]=lsum; __syncthreads();
  for (int o=64;o>0;o>>=1){ if(t<o) s[t]+=s[t+o]; __syncthreads(); }
  float mean = s[0]*(1.0f/384.0f);
  __syncthreads();
  float l2=0.f;
  #pragma unroll
  for (int i=0;i<3;i++){ float dmu=v[i]-mean; l2+=dmu*dmu; }
  s[t]=l2; __syncthreads();
  for (int o=64;o>0;o>>=1){ if(t<o) s[t]+=s[t+o]; __syncthreads(); }
  float var = s[0]*(1.0f/384.0f);
  float rs = 1.0f/sqrtf(var+LEPS);
  #pragma unroll
  for (int i=0;i<3;i++){ int c=t+i*128; out[(size_t)row*DMODEL+c] = (v[i]-mean)*rs*gamma[c]+beta[c]; }
}

// ---------------- depthwise causal conv(k=4) + silu ----------------
__global__ __launch_bounds__(256) void conv_kernel(const float* __restrict__ uz, const float* __restrict__ cw,
                                                   const float* __restrict__ cb, float* __restrict__ uc){
  int gid = blockIdx.x*256 + threadIdx.x;  // NTOK*DINNER
  int d = gid % DINNER;
  int rl = gid / DINNER;
  int l = rl & (NG-1);
  float acc = cb[d];
  #pragma unroll
  for (int k=0;k<4;k++){
    int l2 = l-3+k;
    if (l2 >= 0) acc += uz[(size_t)(rl-3+k)*1536 + d]*cw[d*4+k];
  }
  uc[gid] = acc/(1.0f+__expf(-acc));
}

// ---------------- fused dtproj + SSM scan + skip + gating ----------------
// One thread per (batch, channel); xbc slab for the batch staged in LDS (broadcast reads);
// uc/z software-pipelined; yg written bf16 for the MFMA out-proj.
__global__ __launch_bounds__(256) void scan_fused(const float* __restrict__ uc, const float* __restrict__ xbcg,
                                                  const float* __restrict__ uz, const float* __restrict__ dtw,
                                                  const float* __restrict__ dtb, const float* __restrict__ Alog,
                                                  const float* __restrict__ Dp, ushort_t* __restrict__ yg){
  __shared__ float sxbc[NG*56];  // 28 KB
  const int blk = blockIdx.x;          // NBATCH*3
  const int b = blk/3, chunk = blk%3;
  const int t = threadIdx.x;
  const int d = chunk*256 + t;
  const float* xbcb = xbcg + (size_t)b*NG*56;
  for (int i=t; i<NG*56; i+=256) sxbc[i] = xbcb[i];
  float wdt[DTRANK];
  #pragma unroll
  for (int j=0;j<DTRANK;j++) wdt[j] = dtw[(size_t)d*DTRANK + j];
  const float dtbias = dtb[d];
  float a[DSTATE];
  #pragma unroll
  for (int s=0;s<DSTATE;s++) a[s] = -expf(Alog[(size_t)d*DSTATE+s]);
  const float D_ = Dp[d];
  float h[DSTATE];
  #pragma unroll
  for (int s=0;s<DSTATE;s++) h[s]=0.f;
  __syncthreads();
  const float* ucp = uc + (size_t)b*NG*DINNER + d;
  const float* zp  = uz + (size_t)b*NG*1536 + DINNER + d;
  ushort_t* yp = yg + (size_t)b*NG*DINNER + d;
  float uv = ucp[0], zv = zp[0];
  for (int l=0;l<NG;l++){
    float uv_n = 0.f, zv_n = 0.f;
    if (l < NG-1){ uv_n = ucp[(size_t)(l+1)*DINNER]; zv_n = zp[(size_t)(l+1)*1536]; }
    const float* xr = &sxbc[l*56];
    float accd = dtbias;
    #pragma unroll
    for (int j=0;j<DTRANK;j++) accd += xr[j]*wdt[j];
    float dtv = (accd > 20.0f) ? accd : log1pf(__expf(accd));
    float du = dtv*uv;
    float y = 0.f;
    #pragma unroll
    for (int s=0;s<DSTATE;s++){
      float dA = __expf(dtv*a[s]);
      h[s] = dA*h[s] + du*xr[24+s];
      y += h[s]*xr[40+s];
    }
    float sg = zv/(1.0f+__expf(-zv));
    yp[(size_t)l*DINNER] = f2bf((y + uv*D_)*sg);
    uv = uv_n; zv = zv_n;
  }
}

// ---------------- launch ----------------
extern "C" void kernel_launch(void* const* d_in, const int* in_sizes, int n_in,
                              void* d_out, int out_size, void* d_ws, size_t ws_size,
                              hipStream_t stream){
  const float* pts   = (const float*)d_in[0];
  const float* e1w   = (const float*)d_in[1];
  const float* e1b   = (const float*)d_in[2];
  const float* bn1g  = (const float*)d_in[3];
  const float* bn1b  = (const float*)d_in[4];
  const float* bn1m  = (const float*)d_in[5];
  const float* bn1v  = (const float*)d_in[6];
  const float* e2w   = (const float*)d_in[7];
  const float* e2b   = (const float*)d_in[8];
  const float* e3w   = (const float*)d_in[9];
  const float* e3b   = (const float*)d_in[10];
  const float* bn2g  = (const float*)d_in[11];
  const float* bn2b  = (const float*)d_in[12];
  const float* bn2m  = (const float*)d_in[13];
  const float* bn2v  = (const float*)d_in[14];
  const float* e4w   = (const float*)d_in[15];
  const float* e4b   = (const float*)d_in[16];
  const float* p1w   = (const float*)d_in[17];
  const float* p1b   = (const float*)d_in[18];
  const float* p2w   = (const float*)d_in[19];
  const float* p2b   = (const float*)d_in[20];
  const float* lng   = (const float*)d_in[21];
  const float* lnb   = (const float*)d_in[22];
  const float* inw   = (const float*)d_in[23];
  const float* convw = (const float*)d_in[24];
  const float* convb = (const float*)d_in[25];
  const float* xprojw= (const float*)d_in[26];
  const float* dtw   = (const float*)d_in[27];
  const float* dtb   = (const float*)d_in[28];
  const float* Alog  = (const float*)d_in[29];
  const float* Dp    = (const float*)d_in[30];
  const float* outw  = (const float*)d_in[31];
  const float* nfg   = (const float*)d_in[32];
  const float* nfb   = (const float*)d_in[33];
  float* out = (float*)d_out;

  char* w = (char*)d_ws;
  const size_t O_IDX   = 0;
  const size_t O_CENT  = 8192;
  const size_t O_PG    = 32768;
  const size_t O_A1    = 819200;
  const size_t O_B1    = 819712;
  const size_t O_A2    = 820224;
  const size_t O_B2    = 822272;
  const size_t O_PG1   = 824320;
  const size_t O_POS   = 1872896;
  const size_t O_H     = 5018624;
  const size_t O_RES   = 8164352;
  const size_t O_E2WB  = 11310080;     // 65536
  const size_t O_E3WB  = 11375616;     // 524288
  const size_t O_E4WB  = 11899904;     // 393216
  const size_t O_INWB  = 12293120;     // 14155776 (12 layers in-proj bf16)
  const size_t O_OUTWB = 26448896;     // 7077888  (12 layers out-proj bf16)
  const size_t O_F3B   = 33526784;     // 67108864 (bf16 f3)
  const size_t O_F1B   = 100635648;    // 16777216
  const size_t O_F2B   = 117412864;    // 33554432
  const size_t O_FGB   = 150967296;    // 1048576
  const size_t O_T4B   = O_F1B;        // t4 bf16 (50331648) over dead f1b+f2b exactly
  const size_t O_END   = 152015872;
  // mamba-phase buffers alias the (dead) f3b region (24 MB < 64 MB):
  const size_t O_XLNB  = O_F3B;                    // 1572864
  const size_t O_UZ    = O_F3B + 1572864;          // 12582912
  const size_t O_UC    = O_F3B + 14155776;         // 6291456
  const size_t O_XBC   = O_F3B + 20447232;         // 458752
  const size_t O_YG    = O_F3B + 20905984;         // 3145728 (bf16)
  if (ws_size < O_END) return;

  int*   idx  = (int*)(w+O_IDX);
  float* cent = (float*)(w+O_CENT);
  float* pg   = (float*)(w+O_PG);
  float* a1 = (float*)(w+O_A1); float* b1 = (float*)(w+O_B1);
  float* a2 = (float*)(w+O_A2); float* b2 = (float*)(w+O_B2);
  float* pg1 = (float*)(w+O_PG1);
  float* pos = (float*)(w+O_POS);
  float* hb  = (float*)(w+O_H);
  float* res = (float*)(w+O_RES);
  ushort_t* e2wb = (ushort_t*)(w+O_E2WB);
  ushort_t* e3wb = (ushort_t*)(w+O_E3WB);
  ushort_t* e4wb = (ushort_t*)(w+O_E4WB);
  ushort_t* inwb = (ushort_t*)(w+O_INWB);
  ushort_t* outwb= (ushort_t*)(w+O_OUTWB);
  ushort_t* f1b = (ushort_t*)(w+O_F1B);
  ushort_t* f2b = (ushort_t*)(w+O_F2B);
  ushort_t* fgb = (ushort_t*)(w+O_FGB);
  ushort_t* f3b = (ushort_t*)(w+O_F3B);
  ushort_t* t4b = (ushort_t*)(w+O_T4B);
  ushort_t* xlnb= (ushort_t*)(w+O_XLNB);
  float* uzb = (float*)(w+O_UZ);
  float* ucb = (float*)(w+O_UC);
  float* xbc = (float*)(w+O_XBC);
  ushort_t* yg = (ushort_t*)(w+O_YG);

  // ---- grouping ----
  fps_kernel<<<NBATCH, 256, 0, stream>>>(pts, idx);
  knn_kernel<<<NTOK, 256, 0, stream>>>(pts, idx, pg, cent);
  prep_kernel<<<1, 512, 0, stream>>>(bn1g,bn1b,bn1m,bn1v,e1b, bn2g,bn2b,bn2m,bn2v,e3b, a1,b1,a2,b2);
  cvt_kernel<<<(256*128+255)/256, 256, 0, stream>>>(e2w, e2wb, 256*128);
  cvt_kernel<<<(512*512+255)/256, 256, 0, stream>>>(e3w, e3wb, 512*512);
  cvt_kernel<<<(384*512+255)/256, 256, 0, stream>>>(e4w, e4wb, 384*512);
  cvt_kernel<<<(NLAYER*1536*DMODEL+255)/256, 256, 0, stream>>>(inw, inwb, NLAYER*1536*DMODEL);
  cvt_kernel<<<(NLAYER*DMODEL*DINNER+255)/256, 256, 0, stream>>>(outw, outwb, NLAYER*DMODEL*DINNER);

  // ---- point embedding (bf16 MFMA) ----
  e1_kernel<<<NROW*128/256, 256, 0, stream>>>(pg, e1w, a1, b1, f1b);
  mfma_gemm<1,false,true ><<<dim3(2,512), 256, 0, stream>>>(f1b, nullptr, e2wb, e2b, nullptr, f2b, NROW, 256, 128);
  fgpool_kernel<<<NTOK, 256, 0, stream>>>(f2b, fgb);
  mfma_gemm<2,true ,true ><<<dim3(4,512), 256, 0, stream>>>(f2b, fgb, e3wb, a2, b2, f3b, NROW, 512, 512);
  mfma_gemm<1,false,true ><<<dim3(3,512), 256, 0, stream>>>(f3b, nullptr, e4wb, e4b, nullptr, t4b, NROW, 384, 512);
  p1_kernel<<<NTOK*128/256, 256, 0, stream>>>(cent, p1w, p1b, pg1);
  gemm64<1><<<dim3(6,32), 256, 0, stream>>>(pg1, p2w, p2b, pos, NTOK, 384, 128);
  tokpool_kernel<<<NTOK, 384, 0, stream>>>(t4b, pos, hb);

  // ---- 12 mamba layers ----
  for (int i=0;i<NLAYER;i++){
    if (i==0) ln_kernel<false><<<NTOK,128,0,stream>>>(hb, res, xlnb, lng+(size_t)i*DMODEL, lnb+(size_t)i*DMODEL);
    else      ln_kernel<true ><<<NTOK,128,0,stream>>>(hb, res, xlnb, lng+(size_t)i*DMODEL, lnb+(size_t)i*DMODEL);
    mfma_gemm<0,false,false><<<dim3(12,16),256,0,stream>>>(xlnb, nullptr, inwb+(size_t)i*1536*DMODEL,
                                                           nullptr, nullptr, uzb, NTOK, 1536, DMODEL);
    conv_kernel<<<NTOK*DINNER/256,256,0,stream>>>(uzb, convw+(size_t)i*DINNER*4, convb+(size_t)i*DINNER, ucb);
    gemm64<0><<<dim3(1,32),256,0,stream>>>(ucb, xprojw+(size_t)i*56*DINNER, nullptr, xbc, NTOK, 56, DINNER);
    scan_fused<<<NBATCH*3,256,0,stream>>>(ucb, xbc, uzb, dtw+(size_t)i*DINNER*DTRANK, dtb+(size_t)i*DINNER,
                                          Alog+(size_t)i*DINNER*DSTATE, Dp+(size_t)i*DINNER, yg);
    mfma_gemm<0,false,false><<<dim3(3,16),256,0,stream>>>(yg, nullptr, outwb+(size_t)i*DMODEL*DINNER,
                                                          nullptr, nullptr, hb, NTOK, DMODEL, DINNER);
  }
  final_ln_kernel<<<NTOK,128,0,stream>>>(hb, res, nfg, nfb, out);
}

// Round 7
// 2433.133 us; speedup vs baseline: 2.5469x; 1.2763x over previous
//
#include <hip/hip_runtime.h>
#include <cstddef>
#include <cstdint>

#define NPTS   2048
#define NBATCH 16
#define NG     128
#define NM     32
#define DMODEL 384
#define DINNER 768
#define DSTATE 16
#define DTRANK 24
#define NLAYER 12
#define LEPS   1e-5f
#define NTOK   (NBATCH*NG)      /* 2048 tokens */
#define NROW   (NTOK*NM)        /* 65536 point rows */
#define FLTMAX 3.402823466e+38f

typedef __attribute__((ext_vector_type(8))) short bf16x8;
typedef __attribute__((ext_vector_type(4))) float f32x4;
typedef unsigned short ushort_t;

__device__ __forceinline__ unsigned short f2bf(float f){
  unsigned int u = __float_as_uint(f);
  unsigned int r = (u + 0x7FFFu + ((u>>16)&1u)) >> 16;
  return (unsigned short)r;
}
__device__ __forceinline__ float bf2f(unsigned short h){
  return __uint_as_float(((unsigned int)h)<<16);
}

// ---------------- FPS: points register-resident; LDS only for center lookup ----------------
// Exact jnp semantics: _rn ops in numpy association order; argmax tie-break = lowest index.
__global__ __launch_bounds__(256) void fps_kernel(const float* __restrict__ pts, int* __restrict__ idx){
  __shared__ float sx[NPTS], sy[NPTS], sz[NPTS];
  __shared__ float wbv[4]; __shared__ int wbi[4];
  const int b = blockIdx.x, t = threadIdx.x;
  const float* P = pts + (size_t)b*NPTS*3;
  float px[8], py[8], pz[8], dmin[8];
  #pragma unroll
  for (int j=0;j<8;j++){
    int p = t + j*256;
    float x=P[p*3+0], y=P[p*3+1], z=P[p*3+2];
    px[j]=x; py[j]=y; pz[j]=z; dmin[j]=1e10f;
    sx[p]=x; sy[p]=y; sz[p]=z;
  }
  __syncthreads();
  int cur = 0;
  if (t==0) idx[b*NG+0] = 0;
  for (int it=1; it<NG; ++it){
    float lx=sx[cur], ly=sy[cur], lz=sz[cur];
    float best = -1.0f; int bi = 0;
    #pragma unroll
    for (int j=0;j<8;j++){
      int p = t + j*256;
      float dx=__fsub_rn(px[j],lx), dy=__fsub_rn(py[j],ly), dz=__fsub_rn(pz[j],lz);
      float dd = __fadd_rn(__fadd_rn(__fmul_rn(dx,dx),__fmul_rn(dy,dy)),__fmul_rn(dz,dz));
      float dm = fminf(dmin[j], dd);
      dmin[j]=dm;
      if (dm > best || (dm == best && p < bi)) { best = dm; bi = p; }
    }
    #pragma unroll
    for (int m=1;m<64;m<<=1){
      float ov = __shfl_xor(best, m);
      int   oi = __shfl_xor(bi, m);
      if (ov > best || (ov == best && oi < bi)){ best=ov; bi=oi; }
    }
    if ((t&63)==0){ wbv[t>>6]=best; wbi[t>>6]=bi; }
    __syncthreads();
    float b0=wbv[0]; int i0=wbi[0];
    #pragma unroll
    for (int k2=1;k2<4;k2++){
      float ov=wbv[k2]; int oi=wbi[k2];
      if (ov > b0 || (ov == b0 && oi < i0)){ b0=ov; i0=oi; }
    }
    cur = i0;
    if (t==0) idx[b*NG+it] = cur;
    __syncthreads();
  }
}

// ---------------- kNN grouping: wave shfl argmin + 4-entry merge (2 barriers/pass) ----------------
__global__ __launch_bounds__(256) void knn_kernel(const float* __restrict__ pts, const int* __restrict__ idx,
                                                  float* __restrict__ pg, float* __restrict__ centerb){
  __shared__ float sx[NPTS], sy[NPTS], sz[NPTS], sd[NPTS];
  __shared__ float rv4[4]; __shared__ int ri4[4];
  const int bid = blockIdx.x;
  const int b = bid >> 7;
  const int t = threadIdx.x;
  const float* P = pts + (size_t)b*NPTS*3;
  const int ci = idx[bid];
  const float cx = P[ci*3+0], cy = P[ci*3+1], cz = P[ci*3+2];
  const float cs = __fadd_rn(__fadd_rn(__fmul_rn(cx,cx),__fmul_rn(cy,cy)),__fmul_rn(cz,cz));
  for (int p=t; p<NPTS; p+=256){
    float x=P[p*3+0], y=P[p*3+1], z=P[p*3+2];
    float ps  = __fadd_rn(__fadd_rn(__fmul_rn(x,x),__fmul_rn(y,y)),__fmul_rn(z,z));
    float dot = __fadd_rn(__fadd_rn(__fmul_rn(cx,x),__fmul_rn(cy,y)),__fmul_rn(cz,z));
    float d = __fsub_rn(__fadd_rn(cs,ps), __fmul_rn(2.0f,dot));
    sx[p]=x; sy[p]=y; sz[p]=z; sd[p]=d;
  }
  if (t==0){ centerb[bid*3+0]=cx; centerb[bid*3+1]=cy; centerb[bid*3+2]=cz; }
  __syncthreads();
  for (int m=0;m<NM;m++){
    float bv = FLTMAX; int bp = NPTS;
    #pragma unroll
    for (int j=0;j<8;j++){
      int p = t + j*256;
      float v = sd[p];
      if (v < bv || (v == bv && p < bp)){ bv=v; bp=p; }
    }
    #pragma unroll
    for (int s=1;s<64;s<<=1){
      float ov = __shfl_xor(bv, s);
      int   oi = __shfl_xor(bp, s);
      if (ov < bv || (ov == bv && oi < bp)){ bv=ov; bp=oi; }
    }
    if ((t&63)==0){ rv4[t>>6]=bv; ri4[t>>6]=bp; }
    __syncthreads();
    if (t==0){
      float b0=rv4[0]; int i0=ri4[0];
      #pragma unroll
      for (int k2=1;k2<4;k2++){
        float ov=rv4[k2]; int oi=ri4[k2];
        if (ov < b0 || (ov == b0 && oi < i0)){ b0=ov; i0=oi; }
      }
      size_t orow = ((size_t)bid*NM + m)*3;
      pg[orow+0]=__fsub_rn(sx[i0],cx);
      pg[orow+1]=__fsub_rn(sy[i0],cy);
      pg[orow+2]=__fsub_rn(sz[i0],cz);
      sd[i0]=FLTMAX;
    }
    __syncthreads();
  }
}

// ---------------- folded BN coefficients ----------------
__global__ void prep_kernel(const float* bn1g, const float* bn1b, const float* bn1m, const float* bn1v, const float* e1b,
                            const float* bn2g, const float* bn2b, const float* bn2m, const float* bn2v, const float* e3b,
                            float* a1, float* b1, float* a2, float* b2){
  int t = threadIdx.x;
  if (t<128){ float a = bn1g[t]/sqrtf(bn1v[t]+LEPS); a1[t]=a; b1[t]=(e1b[t]-bn1m[t])*a+bn1b[t]; }
  if (t<512){ float a = bn2g[t]/sqrtf(bn2v[t]+LEPS); a2[t]=a; b2[t]=(e3b[t]-bn2m[t])*a+bn2b[t]; }
}

// ---------------- fp32 -> bf16 convert ----------------
__global__ __launch_bounds__(256) void cvt_kernel(const float* __restrict__ src, ushort_t* __restrict__ dst, int n){
  int i = blockIdx.x*256 + threadIdx.x;
  if (i < n) dst[i] = f2bf(src[i]);
}

// ---------------- tiny K=3 layers ----------------
__global__ __launch_bounds__(256) void e1_kernel(const float* __restrict__ pg, const float* __restrict__ w,
                                                 const float* __restrict__ a1, const float* __restrict__ b1,
                                                 ushort_t* __restrict__ f1b){
  int gid = blockIdx.x*256 + threadIdx.x;      // NROW*128
  int row = gid >> 7, c = gid & 127;
  float x = pg[(size_t)row*3+0], y = pg[(size_t)row*3+1], z = pg[(size_t)row*3+2];
  float v = x*w[c*3+0] + y*w[c*3+1] + z*w[c*3+2];
  f1b[gid] = f2bf(fmaxf(v*a1[c]+b1[c], 0.0f));
}

__global__ __launch_bounds__(256) void p1_kernel(const float* __restrict__ center, const float* __restrict__ w,
                                                 const float* __restrict__ bias, float* __restrict__ o){
  int gid = blockIdx.x*256 + threadIdx.x;      // NTOK*128
  int row = gid >> 7, c = gid & 127;
  float x = center[(size_t)row*3+0], y = center[(size_t)row*3+1], z = center[(size_t)row*3+2];
  float v = x*w[c*3+0]+y*w[c*3+1]+z*w[c*3+2] + bias[c];
  o[gid] = 0.5f*v*(1.0f+erff(v*0.70710678118654752f));  // exact gelu
}

// ---------------- bf16 MFMA GEMM, 128x128 tile (embed path) ----------------
template<int EPI, bool CONCAT, bool OUTBF>
__global__ __launch_bounds__(256) void mfma_gemm(const ushort_t* __restrict__ A, const ushort_t* __restrict__ A2,
                                                 const ushort_t* __restrict__ W, const float* __restrict__ P1,
                                                 const float* __restrict__ P2, void* __restrict__ Cout,
                                                 int M, int N, int K){
  __shared__ short As[128*72];
  __shared__ short Ws[128*72];
  const int tid = threadIdx.x;
  const int bm = blockIdx.y*128, bn = blockIdx.x*128;
  const int lane = tid & 63, wid = tid >> 6;
  const int wm = (wid&1)*64, wn = (wid>>1)*64;
  f32x4 acc[4][4];
  #pragma unroll
  for (int i=0;i<4;i++)
    #pragma unroll
    for (int j=0;j<4;j++) acc[i][j] = (f32x4){0.f,0.f,0.f,0.f};

  for (int kt=0; kt<K; kt+=64){
    #pragma unroll
    for (int p=0;p<4;p++){
      int i = p*256 + tid;
      int row = i>>3, k8 = (i&7)*8;
      const ushort_t* src;
      if (CONCAT){
        int rg = bm+row;
        if (kt < 256) src = A2 + (size_t)(rg>>5)*256 + kt + k8;
        else          src = A  + (size_t)rg*256 + (kt-256) + k8;
      } else {
        src = A + (size_t)(bm+row)*K + kt + k8;
      }
      *(bf16x8*)(As + row*72 + k8) = *(const bf16x8*)src;
      *(bf16x8*)(Ws + row*72 + k8) = *(const bf16x8*)(W + (size_t)(bn+row)*K + kt + k8);
    }
    __syncthreads();
    #pragma unroll
    for (int kc=0;kc<2;kc++){
      bf16x8 af[4], bfr[4];
      #pragma unroll
      for (int mi=0;mi<4;mi++) af[mi]  = *(const bf16x8*)(As + (wm+mi*16+(lane&15))*72 + kc*32 + (lane>>4)*8);
      #pragma unroll
      for (int ni=0;ni<4;ni++) bfr[ni] = *(const bf16x8*)(Ws + (wn+ni*16+(lane&15))*72 + kc*32 + (lane>>4)*8);
      #pragma unroll
      for (int mi=0;mi<4;mi++)
        #pragma unroll
        for (int ni=0;ni<4;ni++)
          acc[mi][ni] = __builtin_amdgcn_mfma_f32_16x16x32_bf16(af[mi], bfr[ni], acc[mi][ni], 0,0,0);
    }
    __syncthreads();
  }
  #pragma unroll
  for (int mi=0;mi<4;mi++){
    #pragma unroll
    for (int ni=0;ni<4;ni++){
      int col = bn + wn + ni*16 + (lane&15);
      #pragma unroll
      for (int r=0;r<4;r++){
        int row = bm + wm + mi*16 + (lane>>4)*4 + r;
        float v = acc[mi][ni][r];
        if (EPI==1) v += P1[col];
        else if (EPI==2) v = fmaxf(v*P1[col]+P2[col], 0.f);
        if (OUTBF) ((ushort_t*)Cout)[(size_t)row*N + col] = f2bf(v);
        else       ((float*)Cout)[(size_t)row*N + col] = v;
      }
    }
  }
}

// ---------------- bf16 MFMA GEMM, 64x64 tile (occupancy for small GEMMs) ----------------
// C[M,N] fp32 = A[M,K]bf16 @ W[N,K]^T bf16. M%64==0, K%64==0, N arbitrary (guarded).
__global__ __launch_bounds__(256) void mfma_gemm64(const ushort_t* __restrict__ A, const ushort_t* __restrict__ W,
                                                   float* __restrict__ C, int M, int N, int K){
  __shared__ short As[64*72];
  __shared__ short Ws[64*72];
  const int tid = threadIdx.x;
  const int bm = blockIdx.y*64, bn = blockIdx.x*64;
  const int lane = tid & 63, wid = tid >> 6;
  const int wm = (wid&1)*32, wn = (wid>>1)*32;
  f32x4 acc[2][2];
  #pragma unroll
  for (int i=0;i<2;i++)
    #pragma unroll
    for (int j=0;j<2;j++) acc[i][j] = (f32x4){0.f,0.f,0.f,0.f};

  for (int kt=0; kt<K; kt+=64){
    #pragma unroll
    for (int p=0;p<2;p++){
      int i = p*256 + tid;        // 512 slots
      int row = i>>3, k8 = (i&7)*8;
      *(bf16x8*)(As + row*72 + k8) = *(const bf16x8*)(A + (size_t)(bm+row)*K + kt + k8);
      bf16x8 wv = (bf16x8){0,0,0,0,0,0,0,0};
      if (bn+row < N) wv = *(const bf16x8*)(W + (size_t)(bn+row)*K + kt + k8);
      *(bf16x8*)(Ws + row*72 + k8) = wv;
    }
    __syncthreads();
    #pragma unroll
    for (int kc=0;kc<2;kc++){
      bf16x8 af[2], bfr[2];
      #pragma unroll
      for (int mi=0;mi<2;mi++) af[mi]  = *(const bf16x8*)(As + (wm+mi*16+(lane&15))*72 + kc*32 + (lane>>4)*8);
      #pragma unroll
      for (int ni=0;ni<2;ni++) bfr[ni] = *(const bf16x8*)(Ws + (wn+ni*16+(lane&15))*72 + kc*32 + (lane>>4)*8);
      #pragma unroll
      for (int mi=0;mi<2;mi++)
        #pragma unroll
        for (int ni=0;ni<2;ni++)
          acc[mi][ni] = __builtin_amdgcn_mfma_f32_16x16x32_bf16(af[mi], bfr[ni], acc[mi][ni], 0,0,0);
    }
    __syncthreads();
  }
  #pragma unroll
  for (int mi=0;mi<2;mi++){
    #pragma unroll
    for (int ni=0;ni<2;ni++){
      int col = bn + wn + ni*16 + (lane&15);
      #pragma unroll
      for (int r=0;r<4;r++){
        int row = bm + wm + mi*16 + (lane>>4)*4 + r;
        if (col < N) C[(size_t)row*N + col] = acc[mi][ni][r];
      }
    }
  }
}

// ---------------- fp32 GEMM, 64x64 tile (pos path only) ----------------
template<int EPI>
__global__ __launch_bounds__(256) void gemm64(const float* __restrict__ A, const float* __restrict__ W,
                                              const float* __restrict__ P1, float* __restrict__ C,
                                              int M, int N, int K){
  __shared__ float As[16][68];
  __shared__ float Ws[16][68];
  const int tid = threadIdx.x;
  const int bm = blockIdx.y*64, bn = blockIdx.x*64;
  const int tx = tid & 15, ty = tid >> 4;
  float acc[4][4];
  #pragma unroll
  for (int i=0;i<4;i++)
    #pragma unroll
    for (int j=0;j<4;j++) acc[i][j]=0.f;
  for (int kt=0; kt<K; kt+=16){
    int row = tid>>2, kq = (tid&3)*4;
    float4 va = *(const float4*)(A + (size_t)(bm+row)*K + kt + kq);
    As[kq+0][row]=va.x; As[kq+1][row]=va.y; As[kq+2][row]=va.z; As[kq+3][row]=va.w;
    float4 vw = make_float4(0.f,0.f,0.f,0.f);
    if (bn+row < N) vw = *(const float4*)(W + (size_t)(bn+row)*K + kt + kq);
    Ws[kq+0][row]=vw.x; Ws[kq+1][row]=vw.y; Ws[kq+2][row]=vw.z; Ws[kq+3][row]=vw.w;
    __syncthreads();
    #pragma unroll
    for (int k=0;k<16;k++){
      float a4[4], b4[4];
      *(float4*)&a4[0] = *(const float4*)&As[k][ty*4];
      *(float4*)&b4[0] = *(const float4*)&Ws[k][tx*4];
      #pragma unroll
      for (int i=0;i<4;i++)
        #pragma unroll
        for (int j=0;j<4;j++) acc[i][j] += a4[i]*b4[j];
    }
    __syncthreads();
  }
  #pragma unroll
  for (int i=0;i<4;i++){
    int rg = bm + ty*4 + i;
    #pragma unroll
    for (int j=0;j<4;j++){
      int n = bn + tx*4 + j;
      if (n < N){
        float v = acc[i][j];
        if (EPI==1) v += P1[n];
        C[(size_t)rg*N + n] = v;
      }
    }
  }
}

// ---------------- max-pools ----------------
__global__ __launch_bounds__(256) void fgpool_kernel(const ushort_t* __restrict__ f2b, ushort_t* __restrict__ fgb){
  int g = blockIdx.x, c = threadIdx.x;
  float m = -FLTMAX;
  for (int mm=0;mm<NM;mm++) m = fmaxf(m, bf2f(f2b[((size_t)(g*NM+mm))*256 + c]));
  fgb[(size_t)g*256+c]=f2bf(m);
}
__global__ __launch_bounds__(384) void tokpool_kernel(const ushort_t* __restrict__ t4b, const float* __restrict__ pos,
                                                      float* __restrict__ h){
  int g = blockIdx.x, c = threadIdx.x;
  float m = -FLTMAX;
  for (int mm=0;mm<NM;mm++) m = fmaxf(m, bf2f(t4b[((size_t)(g*NM+mm))*DMODEL + c]));
  h[(size_t)g*DMODEL+c] = m + pos[(size_t)g*DMODEL+c];
}

// ---------------- LayerNorm (+residual update), bf16 xln out ----------------
template<bool ADD>
__global__ __launch_bounds__(128) void ln_kernel(const float* __restrict__ hbuf, float* __restrict__ res,
                                                 ushort_t* __restrict__ xlnb, const float* __restrict__ gamma,
                                                 const float* __restrict__ beta){
  __shared__ float s[128];
  int row = blockIdx.x, t = threadIdx.x;
  const float* hr = hbuf + (size_t)row*DMODEL;
  float* rr = res + (size_t)row*DMODEL;
  float v[3]; float lsum=0.f;
  #pragma unroll
  for (int i=0;i<3;i++){ int c=t+i*128; float x=hr[c]; if(ADD) x+=rr[c]; v[i]=x; lsum+=x; }
  #pragma unroll
  for (int i=0;i<3;i++) rr[t+i*128]=v[i];
  s[t]=lsum; __syncthreads();
  for (int o=64;o>0;o>>=1){ if(t<o) s[t]+=s[t+o]; __syncthreads(); }
  float mean = s[0]*(1.0f/384.0f);
  __syncthreads();
  float l2=0.f;
  #pragma unroll
  for (int i=0;i<3;i++){ float dmu=v[i]-mean; l2+=dmu*dmu; }
  s[t]=l2; __syncthreads();
  for (int o=64;o>0;o>>=1){ if(t<o) s[t]+=s[t+o]; __syncthreads(); }
  float var = s[0]*(1.0f/384.0f);
  float rs = 1.0f/sqrtf(var+LEPS);
  #pragma unroll
  for (int i=0;i<3;i++){ int c=t+i*128; xlnb[(size_t)row*DMODEL+c] = f2bf((v[i]-mean)*rs*gamma[c]+beta[c]); }
}

__global__ __launch_bounds__(128) void final_ln_kernel(const float* __restrict__ hbuf, const float* __restrict__ res,
                                                       const float* __restrict__ gamma, const float* __restrict__ beta,
                                                       float* __restrict__ out){
  __shared__ float s[128];
  int row = blockIdx.x, t = threadIdx.x;
  const float* hr = hbuf + (size_t)row*DMODEL;
  const float* rr = res + (size_t)row*DMODEL;
  float v[3]; float lsum=0.f;
  #pragma unroll
  for (int i=0;i<3;i++){ int c=t+i*128; float x=hr[c]+rr[c]; v[i]=x; lsum+=x; }
  s[t]=lsum; __syncthreads();
  for (int o=64;o>0;o>>=1){ if(t<o) s[t]+=s[t+o]; __syncthreads(); }
  float mean = s[0]*(1.0f/384.0f);
  __syncthreads();
  float l2=0.f;
  #pragma unroll
  for (int i=0;i<3;i++){ float dmu=v[i]-mean; l2+=dmu*dmu; }
  s[t]=l2; __syncthreads();
  for (int o=64;o>0;o>>=1){ if(t<o) s[t]+=s[t+o]; __syncthreads(); }
  float var = s[0]*(1.0f/384.0f);
  float rs = 1.0f/sqrtf(var+LEPS);
  #pragma unroll
  for (int i=0;i<3;i++){ int c=t+i*128; out[(size_t)row*DMODEL+c] = (v[i]-mean)*rs*gamma[c]+beta[c]; }
}

// ---------------- depthwise causal conv(k=4) + silu; dual output fp32+bf16 ----------------
__global__ __launch_bounds__(256) void conv_kernel(const float* __restrict__ uz, const float* __restrict__ cw,
                                                   const float* __restrict__ cb, float* __restrict__ uc,
                                                   ushort_t* __restrict__ ucb16){
  int gid = blockIdx.x*256 + threadIdx.x;  // NTOK*DINNER
  int d = gid % DINNER;
  int rl = gid / DINNER;
  int l = rl & (NG-1);
  float acc = cb[d];
  #pragma unroll
  for (int k=0;k<4;k++){
    int l2 = l-3+k;
    if (l2 >= 0) acc += uz[(size_t)(rl-3+k)*1536 + d]*cw[d*4+k];
  }
  float v = acc/(1.0f+__expf(-acc));
  uc[gid] = v;
  ucb16[gid] = f2bf(v);
}

// ---------------- fused dtproj + SSM scan + skip + gating ----------------
__global__ __launch_bounds__(256) void scan_fused(const float* __restrict__ uc, const float* __restrict__ xbcg,
                                                  const float* __restrict__ uz, const float* __restrict__ dtw,
                                                  const float* __restrict__ dtb, const float* __restrict__ Alog,
                                                  const float* __restrict__ Dp, ushort_t* __restrict__ yg){
  __shared__ float sxbc[NG*56];  // 28 KB
  const int blk = blockIdx.x;          // NBATCH*3
  const int b = blk/3, chunk = blk%3;
  const int t = threadIdx.x;
  const int d = chunk*256 + t;
  const float* xbcb = xbcg + (size_t)b*NG*56;
  for (int i=t; i<NG*56; i+=256) sxbc[i] = xbcb[i];
  float4 wdt4[6];
  const float4* dtwp = (const float4*)(dtw + (size_t)d*DTRANK);  // 96B rows, 16B aligned
  #pragma unroll
  for (int j=0;j<6;j++) wdt4[j] = dtwp[j];
  const float dtbias = dtb[d];
  float a[DSTATE];
  #pragma unroll
  for (int s=0;s<DSTATE;s++) a[s] = -expf(Alog[(size_t)d*DSTATE+s]);
  const float D_ = Dp[d];
  float h[DSTATE];
  #pragma unroll
  for (int s=0;s<DSTATE;s++) h[s]=0.f;
  __syncthreads();
  const float* ucp = uc + (size_t)b*NG*DINNER + d;
  const float* zp  = uz + (size_t)b*NG*1536 + DINNER + d;
  ushort_t* yp = yg + (size_t)b*NG*DINNER + d;
  float uv = ucp[0], zv = zp[0];
  for (int l=0;l<NG;l++){
    float uv_n = 0.f, zv_n = 0.f;
    if (l < NG-1){ uv_n = ucp[(size_t)(l+1)*DINNER]; zv_n = zp[(size_t)(l+1)*1536]; }
    const float4* x4 = (const float4*)(sxbc + l*56);   // 224B rows, 16B aligned
    float accd = dtbias;
    #pragma unroll
    for (int j=0;j<6;j++){
      float4 q = x4[j];
      accd += q.x*wdt4[j].x + q.y*wdt4[j].y + q.z*wdt4[j].z + q.w*wdt4[j].w;
    }
    float dtv = (accd > 20.0f) ? accd : log1pf(__expf(accd));
    float du = dtv*uv;
    float4 B0=x4[6], B1=x4[7], B2=x4[8], B3=x4[9];
    float4 C0=x4[10], C1=x4[11], C2=x4[12], C3=x4[13];
    float Bs[16] = {B0.x,B0.y,B0.z,B0.w,B1.x,B1.y,B1.z,B1.w,B2.x,B2.y,B2.z,B2.w,B3.x,B3.y,B3.z,B3.w};
    float Cs[16] = {C0.x,C0.y,C0.z,C0.w,C1.x,C1.y,C1.z,C1.w,C2.x,C2.y,C2.z,C2.w,C3.x,C3.y,C3.z,C3.w};
    float y = 0.f;
    #pragma unroll
    for (int s=0;s<DSTATE;s++){
      float dA = __expf(dtv*a[s]);
      h[s] = dA*h[s] + du*Bs[s];
      y += h[s]*Cs[s];
    }
    float sg = zv/(1.0f+__expf(-zv));
    yp[(size_t)l*DINNER] = f2bf((y + uv*D_)*sg);
    uv = uv_n; zv = zv_n;
  }
}

// ---------------- launch ----------------
extern "C" void kernel_launch(void* const* d_in, const int* in_sizes, int n_in,
                              void* d_out, int out_size, void* d_ws, size_t ws_size,
                              hipStream_t stream){
  const float* pts   = (const float*)d_in[0];
  const float* e1w   = (const float*)d_in[1];
  const float* e1b   = (const float*)d_in[2];
  const float* bn1g  = (const float*)d_in[3];
  const float* bn1b  = (const float*)d_in[4];
  const float* bn1m  = (const float*)d_in[5];
  const float* bn1v  = (const float*)d_in[6];
  const float* e2w   = (const float*)d_in[7];
  const float* e2b   = (const float*)d_in[8];
  const float* e3w   = (const float*)d_in[9];
  const float* e3b   = (const float*)d_in[10];
  const float* bn2g  = (const float*)d_in[11];
  const float* bn2b  = (const float*)d_in[12];
  const float* bn2m  = (const float*)d_in[13];
  const float* bn2v  = (const float*)d_in[14];
  const float* e4w   = (const float*)d_in[15];
  const float* e4b   = (const float*)d_in[16];
  const float* p1w   = (const float*)d_in[17];
  const float* p1b   = (const float*)d_in[18];
  const float* p2w   = (const float*)d_in[19];
  const float* p2b   = (const float*)d_in[20];
  const float* lng   = (const float*)d_in[21];
  const float* lnb   = (const float*)d_in[22];
  const float* inw   = (const float*)d_in[23];
  const float* convw = (const float*)d_in[24];
  const float* convb = (const float*)d_in[25];
  const float* xprojw= (const float*)d_in[26];
  const float* dtw   = (const float*)d_in[27];
  const float* dtb   = (const float*)d_in[28];
  const float* Alog  = (const float*)d_in[29];
  const float* Dp    = (const float*)d_in[30];
  const float* outw  = (const float*)d_in[31];
  const float* nfg   = (const float*)d_in[32];
  const float* nfb   = (const float*)d_in[33];
  float* out = (float*)d_out;

  char* w = (char*)d_ws;
  const size_t O_IDX   = 0;
  const size_t O_CENT  = 8192;
  const size_t O_PG    = 32768;
  const size_t O_A1    = 819200;
  const size_t O_B1    = 819712;
  const size_t O_A2    = 820224;
  const size_t O_B2    = 822272;
  const size_t O_PG1   = 824320;
  const size_t O_POS   = 1872896;
  const size_t O_H     = 5018624;
  const size_t O_RES   = 8164352;
  const size_t O_E2WB  = 11310080;     // 65536
  const size_t O_E3WB  = 11375616;     // 524288
  const size_t O_E4WB  = 11899904;     // 393216
  const size_t O_INWB  = 12293120;     // 14155776
  const size_t O_OUTWB = 26448896;     // 7077888
  const size_t O_XPWB  = 33526784;     // 1032192
  const size_t O_F3B   = 34558976;     // 67108864 (bf16 f3)
  const size_t O_F1B   = 101667840;    // 16777216
  const size_t O_F2B   = 118445056;    // 33554432
  const size_t O_FGB   = 151999488;    // 1048576
  const size_t O_T4B   = O_F1B;        // t4 bf16 (50331648) over dead f1b+f2b exactly
  const size_t O_END   = 153048064;
  // mamba-phase buffers alias the (dead) f3b region:
  const size_t O_XLNB  = O_F3B;                    // 1572864
  const size_t O_UZ    = O_F3B + 1572864;          // 12582912
  const size_t O_UC    = O_F3B + 14155776;         // 6291456
  const size_t O_XBC   = O_F3B + 20447232;         // 458752
  const size_t O_YG    = O_F3B + 20905984;         // 3145728
  const size_t O_UCBB  = O_F3B + 24051712;         // 3145728 (bf16 uc)
  if (ws_size < O_END) return;

  int*   idx  = (int*)(w+O_IDX);
  float* cent = (float*)(w+O_CENT);
  float* pg   = (float*)(w+O_PG);
  float* a1 = (float*)(w+O_A1); float* b1 = (float*)(w+O_B1);
  float* a2 = (float*)(w+O_A2); float* b2 = (float*)(w+O_B2);
  float* pg1 = (float*)(w+O_PG1);
  float* pos = (float*)(w+O_POS);
  float* hb  = (float*)(w+O_H);
  float* res = (float*)(w+O_RES);
  ushort_t* e2wb = (ushort_t*)(w+O_E2WB);
  ushort_t* e3wb = (ushort_t*)(w+O_E3WB);
  ushort_t* e4wb = (ushort_t*)(w+O_E4WB);
  ushort_t* inwb = (ushort_t*)(w+O_INWB);
  ushort_t* outwb= (ushort_t*)(w+O_OUTWB);
  ushort_t* xpwb = (ushort_t*)(w+O_XPWB);
  ushort_t* f1b = (ushort_t*)(w+O_F1B);
  ushort_t* f2b = (ushort_t*)(w+O_F2B);
  ushort_t* fgb = (ushort_t*)(w+O_FGB);
  ushort_t* f3b = (ushort_t*)(w+O_F3B);
  ushort_t* t4b = (ushort_t*)(w+O_T4B);
  ushort_t* xlnb= (ushort_t*)(w+O_XLNB);
  float* uzb = (float*)(w+O_UZ);
  float* ucb = (float*)(w+O_UC);
  float* xbc = (float*)(w+O_XBC);
  ushort_t* yg = (ushort_t*)(w+O_YG);
  ushort_t* ucbb = (ushort_t*)(w+O_UCBB);

  // ---- grouping ----
  fps_kernel<<<NBATCH, 256, 0, stream>>>(pts, idx);
  knn_kernel<<<NTOK, 256, 0, stream>>>(pts, idx, pg, cent);
  prep_kernel<<<1, 512, 0, stream>>>(bn1g,bn1b,bn1m,bn1v,e1b, bn2g,bn2b,bn2m,bn2v,e3b, a1,b1,a2,b2);
  cvt_kernel<<<(256*128+255)/256, 256, 0, stream>>>(e2w, e2wb, 256*128);
  cvt_kernel<<<(512*512+255)/256, 256, 0, stream>>>(e3w, e3wb, 512*512);
  cvt_kernel<<<(384*512+255)/256, 256, 0, stream>>>(e4w, e4wb, 384*512);
  cvt_kernel<<<(NLAYER*1536*DMODEL+255)/256, 256, 0, stream>>>(inw, inwb, NLAYER*1536*DMODEL);
  cvt_kernel<<<(NLAYER*DMODEL*DINNER+255)/256, 256, 0, stream>>>(outw, outwb, NLAYER*DMODEL*DINNER);
  cvt_kernel<<<(NLAYER*56*DINNER+255)/256, 256, 0, stream>>>(xprojw, xpwb, NLAYER*56*DINNER);

  // ---- point embedding (bf16 MFMA) ----
  e1_kernel<<<NROW*128/256, 256, 0, stream>>>(pg, e1w, a1, b1, f1b);
  mfma_gemm<1,false,true ><<<dim3(2,512), 256, 0, stream>>>(f1b, nullptr, e2wb, e2b, nullptr, f2b, NROW, 256, 128);
  fgpool_kernel<<<NTOK, 256, 0, stream>>>(f2b, fgb);
  mfma_gemm<2,true ,true ><<<dim3(4,512), 256, 0, stream>>>(f2b, fgb, e3wb, a2, b2, f3b, NROW, 512, 512);
  mfma_gemm<1,false,true ><<<dim3(3,512), 256, 0, stream>>>(f3b, nullptr, e4wb, e4b, nullptr, t4b, NROW, 384, 512);
  p1_kernel<<<NTOK*128/256, 256, 0, stream>>>(cent, p1w, p1b, pg1);
  gemm64<1><<<dim3(6,32), 256, 0, stream>>>(pg1, p2w, p2b, pos, NTOK, 384, 128);
  tokpool_kernel<<<NTOK, 384, 0, stream>>>(t4b, pos, hb);

  // ---- 12 mamba layers ----
  for (int i=0;i<NLAYER;i++){
    if (i==0) ln_kernel<false><<<NTOK,128,0,stream>>>(hb, res, xlnb, lng+(size_t)i*DMODEL, lnb+(size_t)i*DMODEL);
    else      ln_kernel<true ><<<NTOK,128,0,stream>>>(hb, res, xlnb, lng+(size_t)i*DMODEL, lnb+(size_t)i*DMODEL);
    mfma_gemm64<<<dim3(24,32),256,0,stream>>>(xlnb, inwb+(size_t)i*1536*DMODEL, uzb, NTOK, 1536, DMODEL);
    conv_kernel<<<NTOK*DINNER/256,256,0,stream>>>(uzb, convw+(size_t)i*DINNER*4, convb+(size_t)i*DINNER, ucb, ucbb);
    mfma_gemm64<<<dim3(1,32),256,0,stream>>>(ucbb, xpwb+(size_t)i*56*DINNER, xbc, NTOK, 56, DINNER);
    scan_fused<<<NBATCH*3,256,0,stream>>>(ucb, xbc, uzb, dtw+(size_t)i*DINNER*DTRANK, dtb+(size_t)i*DINNER,
                                          Alog+(size_t)i*DINNER*DSTATE, Dp+(size_t)i*DINNER, yg);
    mfma_gemm64<<<dim3(6,32),256,0,stream>>>(yg, outwb+(size_t)i*DMODEL*DINNER, hb, NTOK, DMODEL, DINNER);
  }
  final_ln_kernel<<<NTOK,128,0,stream>>>(hb, res, nfg, nfb, out);
}